// Round 7
// baseline (19878.595 us; speedup 1.0000x reference)
//
#include <hip/hip_runtime.h>
#include <hip/hip_bf16.h>
#include <cstdint>
#include <cstddef>

typedef __bf16 bf16x8 __attribute__((ext_vector_type(8)));
typedef float f32x4 __attribute__((ext_vector_type(4)));
typedef unsigned short ushort_t;

// sizes: B=256, T=256, ZS=128, ZT=64, H=512, 3H=1536

// ---------------- workspace layout (float offsets)
static constexpr size_t ACC0 = 0;                 // [256][1536] f32 static xp0 (+b_ih0)
static constexpr size_t SHH  = 393216;            // [256][512] static_h
static constexpr size_t HID  = 524288;            // [256][512]
static constexpr size_t H0F  = 655360;            // [2][256][512] f32 ping-pong h0
static constexpr size_t H1F  = 917504;            // [2][256][512] f32 ping-pong h1
static constexpr size_t LOGB = 1179648;           // [256][256][64] f32 head logits
static constexpr size_t WTH  = 5373952;           // [512][64] f32 gathered head weights
static constexpr size_t WGB  = 5406720;           // 64 cs x 73728 ush  (B LDS images)
static constexpr size_t WGA  = 7766016;           // 64 cs x 41472 ush  (A LDS images)
static constexpr size_t WGC  = 9093120;           // 4 slices x 24576 ush (C LDS images)
static constexpr size_t BARO = 9142272;           // barrier (16 u32)
// pre-loop overlays in LOGB (consumed before persist writes LOGB)
static constexpr size_t FC1T = LOGB;
static constexpr size_t FC2T = LOGB + 65536;
static constexpr size_t WIS  = FC2T + 262144;

// ---------------- output layout (float offsets)
static constexpr size_t O_SCONT = 0;
static constexpr size_t O_SCAT  = 4096;
static constexpr size_t O_TCONT = 6656;
static constexpr size_t O_IRR0  = 2103808;
static constexpr size_t O_IRR1  = 2234880;
static constexpr size_t O_CAT0  = 2365952;
static constexpr size_t O_CAT1  = 2890240;
static constexpr size_t O_VMASK = 3938816;
static constexpr size_t O_VTIME = 4004352;

// ---------------- LDS layout (bytes), role-dependent
static constexpr int LDS_BYTES = 159744;
// B: W 0..147455 | redRZ 147456 (+8192) | redN 155648 (+4096)
static constexpr int B_RZRED = 147456;
static constexpr int B_NRED  = 155648;
// A: W 0..82943 | WC 82944 (+49152) | redRZ 132096 | redNH 140288 | redNI 144384 | redC 148480
static constexpr int A_WC    = 82944;
static constexpr int A_RZRED = 132096;
static constexpr int A_NHRED = 140288;
static constexpr int A_NIRED = 144384;
static constexpr int A_CRED  = 148480;

// ---------------- threefry2x32-20
__host__ __device__ inline void tf2x32(unsigned k0, unsigned k1, unsigned x0, unsigned x1,
                                       unsigned* o0, unsigned* o1) {
  unsigned ks2 = k0 ^ k1 ^ 0x1BD11BDAu;
#define TFR(r) { x0 += x1; x1 = (x1 << (r)) | (x1 >> (32 - (r))); x1 ^= x0; }
  x0 += k0; x1 += k1;
  TFR(13) TFR(15) TFR(26) TFR(6)
  x0 += k1; x1 += ks2 + 1u;
  TFR(17) TFR(29) TFR(16) TFR(24)
  x0 += ks2; x1 += k0 + 2u;
  TFR(13) TFR(15) TFR(26) TFR(6)
  x0 += k0; x1 += k1 + 3u;
  TFR(17) TFR(29) TFR(16) TFR(24)
  x0 += k1; x1 += ks2 + 4u;
  TFR(13) TFR(15) TFR(26) TFR(6)
  x0 += ks2; x1 += k0 + 5u;
#undef TFR
  *o0 = x0; *o1 = x1;
}

__device__ inline float rng_u01(unsigned k0, unsigned k1, unsigned idx) {
  unsigned o0, o1;
  tf2x32(k0, k1, 0u, idx, &o0, &o1);
  unsigned bits = o0 ^ o1;
  return __uint_as_float((bits >> 9) | 0x3f800000u) - 1.0f;
}

__device__ inline float sigmoidf_(float x) { return 1.0f / (1.0f + expf(-x)); }

// ---------------- tiled transpose
__global__ __launch_bounds__(256) void transpose_k(const float* __restrict__ src, float* __restrict__ dst,
                                                   int J, int K, int srcStride, int dstStride) {
  __shared__ float tile[32][33];
  int kb = blockIdx.x * 32, jb = blockIdx.y * 32;
  int tx = threadIdx.x & 31, ty = threadIdx.x >> 5;
  #pragma unroll
  for (int r = 0; r < 4; ++r) {
    int j = jb + ty + r * 8, k = kb + tx;
    if (j < J && k < K) tile[ty + r * 8][tx] = src[(size_t)j * srcStride + k];
  }
  __syncthreads();
  #pragma unroll
  for (int r = 0; r < 4; ++r) {
    int k = kb + ty + r * 8, j = jb + tx;
    if (k < K && j < J) dst[(size_t)k * dstStride + j] = tile[tx][ty + r * 8];
  }
}

// ---------------- gather head weights into wtH[512][64] (cols 60..63 zero)
__global__ void hgather_k(const float* __restrict__ time_w, const float* __restrict__ visit_w,
                          const float* __restrict__ tcont_w, const float* __restrict__ irr0_w,
                          const float* __restrict__ irr1_w, const float* __restrict__ cat0_w,
                          const float* __restrict__ cat1_w, float* __restrict__ wtH) {
  int c = blockIdx.x;
  if (c >= 60) {
    for (int k = threadIdx.x; k < 512; k += blockDim.x) wtH[(size_t)k * 64 + c] = 0.0f;
    return;
  }
  const float* src;
  if (c == 0) src = time_w;
  else if (c == 1) src = visit_w;
  else if (c < 34) src = tcont_w + (size_t)(c - 2) * 512;
  else if (c == 34) src = irr0_w;
  else if (c == 35) src = irr1_w;
  else if (c < 44) src = cat0_w + (size_t)(c - 36) * 512;
  else src = cat1_w + (size_t)(c - 44) * 512;
  for (int k = threadIdx.x; k < 512; k += blockDim.x) wtH[(size_t)k * 64 + c] = src[k];
}

// ---------------- fp32 GEMM (pre-loop static path)
__global__ __launch_bounds__(128) void gemm_k(const float* __restrict__ in, const float* __restrict__ wT,
                                              const float* __restrict__ bias, float* __restrict__ out,
                                              int M, int K, int J, int relu) {
  __shared__ float ibuf[64][34];
  __shared__ float wbuf[64][36];
  int jt = blockIdx.x % (J >> 5), mt = blockIdx.x / (J >> 5);
  int m0 = mt * 32, j0 = jt * 32;
  int tid = threadIdx.x;
  int mq = tid & 15, jq = tid >> 4;
  float acc[2][4] = {{0.f, 0.f, 0.f, 0.f}, {0.f, 0.f, 0.f, 0.f}};
  for (int kc = 0; kc < K; kc += 64) {
    __syncthreads();
    #pragma unroll
    for (int i = 0; i < 16; ++i) {
      int lin = i * 128 + tid;
      int k = lin & 63, m = lin >> 6;
      ibuf[k][m] = in[(size_t)(m0 + m) * K + kc + k];
    }
    #pragma unroll
    for (int i = 0; i < 16; ++i) {
      int lin = i * 128 + tid;
      int c = lin & 31, k = lin >> 5;
      wbuf[k][c] = wT[(size_t)(kc + k) * J + j0 + c];
    }
    __syncthreads();
    #pragma unroll 8
    for (int k = 0; k < 64; ++k) {
      float i0 = ibuf[k][2 * mq], i1 = ibuf[k][2 * mq + 1];
      const float4 w = *(const float4*)&wbuf[k][4 * jq];
      acc[0][0] += i0 * w.x; acc[0][1] += i0 * w.y; acc[0][2] += i0 * w.z; acc[0][3] += i0 * w.w;
      acc[1][0] += i1 * w.x; acc[1][1] += i1 * w.y; acc[1][2] += i1 * w.z; acc[1][3] += i1 * w.w;
    }
  }
  #pragma unroll
  for (int mi = 0; mi < 2; ++mi)
    #pragma unroll
    for (int ji = 0; ji < 4; ++ji) {
      int j = j0 + 4 * jq + ji;
      float v = acc[mi][ji] + bias[j];
      if (relu) v = fmaxf(v, 0.0f);
      out[(size_t)(m0 + 2 * mq + mi) * J + j] = v;
    }
}

// ---------------- split helpers
__device__ inline ushort_t split_pick(float v, int spl) {
  __bf16 t0 = (__bf16)v; float r1 = v - (float)t0;
  __bf16 t1 = (__bf16)r1; float r2 = r1 - (float)t1;
  __bf16 t2 = (__bf16)r2;
  __bf16 t = (spl == 0) ? t0 : ((spl == 1) ? t1 : t2);
  return __builtin_bit_cast(ushort_t, t);
}

__device__ inline void split3v(const float* v8, bf16x8& a0, bf16x8& a1, bf16x8& a2) {
  #pragma unroll
  for (int j = 0; j < 8; ++j) {
    float v = v8[j];
    __bf16 t0 = (__bf16)v; float r1 = v - (float)t0;
    __bf16 t1 = (__bf16)r1; float r2 = r1 - (float)t1;
    a0[j] = t0; a1[j] = t1; a2[j] = (__bf16)r2;
  }
}

// ---------------- arrange kernels: build per-block LDS weight images
// B image per cs (73728 ush): [kc 0..31][spl 0..2]{ rz-frag 512 ush | n-frag 256 ush }
// rz-frag elem(l,j): c=l&15, gate = c<8?r:z, hcol=cs*8+(c&7), k=kc*32+(l>>4)*8+j
// n-frag  elem(l2,j): lq=l2>>3, c=l2&7, hcol=cs*8+c, k=kc*32+lq*8+j (gate n)
__global__ __launch_bounds__(256) void arrB_k(const float* __restrict__ w_ih1,
                                              const float* __restrict__ w_hh1,
                                              ushort_t* __restrict__ dst) {
  int id = blockIdx.x * 256 + threadIdx.x;
  if (id >= 64 * 32 * 3 * 96) return;
  int u = id % 96; int r = id / 96;
  int spl = r % 3; r /= 3;
  int kc = r % 32; int cs = r / 32;
  size_t base = (size_t)cs * 73728 + (size_t)(kc * 3 + spl) * 768;
  if (u < 64) {
    int c = u & 15; int gate = (c < 8) ? 0 : 1; int hcol = cs * 8 + (c & 7);
    int grow = gate * 512 + hcol;
    #pragma unroll
    for (int j = 0; j < 8; ++j) {
      int k = kc * 32 + (u >> 4) * 8 + j;
      float v = (k < 512) ? w_ih1[(size_t)grow * 512 + k] : w_hh1[(size_t)grow * 512 + k - 512];
      dst[base + u * 8 + j] = split_pick(v, spl);
    }
  } else {
    int l2 = u - 64; int lq = l2 >> 3, c = l2 & 7; int grow = 1024 + cs * 8 + c;
    #pragma unroll
    for (int j = 0; j < 8; ++j) {
      int k = kc * 32 + lq * 8 + j;
      float v = (k < 512) ? w_ih1[(size_t)grow * 512 + k] : w_hh1[(size_t)grow * 512 + k - 512];
      dst[base + 512 + l2 * 8 + j] = split_pick(v, spl);
    }
  }
}

// A image per cs (41472 ush): [kc 0..17][spl]{ rz 512 | n 256 }; K: 0..511=w_hh0, 512..575=w_ih0[:, :64]
__global__ __launch_bounds__(256) void arrA_k(const float* __restrict__ w_hh0,
                                              const float* __restrict__ w_ih0,
                                              ushort_t* __restrict__ dst) {
  int id = blockIdx.x * 256 + threadIdx.x;
  if (id >= 64 * 18 * 3 * 96) return;
  int u = id % 96; int r = id / 96;
  int spl = r % 3; r /= 3;
  int kc = r % 18; int cs = r / 18;
  size_t base = (size_t)cs * 41472 + (size_t)(kc * 3 + spl) * 768;
  if (u < 64) {
    int c = u & 15; int gate = (c < 8) ? 0 : 1; int hcol = cs * 8 + (c & 7);
    int grow = gate * 512 + hcol;
    #pragma unroll
    for (int j = 0; j < 8; ++j) {
      int k = kc * 32 + (u >> 4) * 8 + j;
      float v = (k < 512) ? w_hh0[(size_t)grow * 512 + k] : w_ih0[(size_t)grow * 576 + k - 512];
      dst[base + u * 8 + j] = split_pick(v, spl);
    }
  } else {
    int l2 = u - 64; int lq = l2 >> 3, c = l2 & 7; int grow = 1024 + cs * 8 + c;
    #pragma unroll
    for (int j = 0; j < 8; ++j) {
      int k = kc * 32 + lq * 8 + j;
      float v = (k < 512) ? w_hh0[(size_t)grow * 512 + k] : w_ih0[(size_t)grow * 576 + k - 512];
      dst[base + 512 + l2 * 8 + j] = split_pick(v, spl);
    }
  }
}

// C image per slice (24576 ush): [kc 0..15][spl][full 16-col frag 512 ush]
__global__ __launch_bounds__(256) void arrC_k(const float* __restrict__ wtH,
                                              ushort_t* __restrict__ dst) {
  int id = blockIdx.x * 256 + threadIdx.x;
  if (id >= 4 * 16 * 3 * 64) return;
  int l = id & 63; int r = id >> 6;
  int spl = r % 3; r /= 3;
  int kc = r % 16; int sl = r / 16;
  size_t base = (size_t)sl * 24576 + (size_t)(kc * 3 + spl) * 512;
  int c = sl * 16 + (l & 15);
  #pragma unroll
  for (int j = 0; j < 8; ++j) {
    int k = kc * 32 + (l >> 4) * 8 + j;
    dst[base + l * 8 + j] = split_pick(wtH[(size_t)k * 64 + c], spl);
  }
}

// ---------------- MFMA helpers
#define MFMA_(A, W, C) __builtin_amdgcn_mfma_f32_16x16x32_bf16((A), (W), (C), 0, 0, 0)

__device__ inline f32x4 mm6w(f32x4 acc, bf16x8 a0, bf16x8 a1, bf16x8 a2,
                             bf16x8 w0, bf16x8 w1, bf16x8 w2) {
  acc = MFMA_(a0, w0, acc); acc = MFMA_(a0, w1, acc); acc = MFMA_(a1, w0, acc);
  acc = MFMA_(a1, w1, acc); acc = MFMA_(a0, w2, acc); acc = MFMA_(a2, w0, acc);
  return acc;
}

__device__ inline bf16x8 ldsb8(const void* p) { return *(const bf16x8*)p; }

struct HeadPtrs {
  const float *time_b, *visit_b, *tcont_b, *irr0_b, *irr1_b, *cat0_b, *cat1_b;
};

__device__ inline float head_bias(const HeadPtrs& hp, int c) {
  if (c == 0) return hp.time_b[0];
  if (c == 1) return hp.visit_b[0];
  if (c < 34) return hp.tcont_b[c - 2];
  if (c == 34) return hp.irr0_b[0];
  if (c == 35) return hp.irr1_b[0];
  if (c < 44) return hp.cat0_b[c - 36];
  return hp.cat1_b[c - 44];
}

// ---------------- two-level grid barrier (256 blocks, 8 classes of 32)
__device__ inline void gridbar(unsigned* bar, unsigned* bgen) {
  __syncthreads();
  if (threadIdx.x == 0) {
    __threadfence();
    const unsigned g0 = *bgen;
    const int cls = blockIdx.x & 7;
    unsigned t = __hip_atomic_fetch_add(&bar[8 + cls], 1u, __ATOMIC_ACQ_REL, __HIP_MEMORY_SCOPE_AGENT);
    bool done = false;
    if (t == 31u) {
      unsigned t2 = __hip_atomic_fetch_add(&bar[0], 1u, __ATOMIC_ACQ_REL, __HIP_MEMORY_SCOPE_AGENT);
      if (t2 == 7u) {
        #pragma unroll
        for (int x = 0; x < 8; ++x)
          __hip_atomic_store(&bar[8 + x], 0u, __ATOMIC_RELAXED, __HIP_MEMORY_SCOPE_AGENT);
        __hip_atomic_store(&bar[0], 0u, __ATOMIC_RELAXED, __HIP_MEMORY_SCOPE_AGENT);
        __threadfence();
        __hip_atomic_fetch_add(&bar[1], 1u, __ATOMIC_ACQ_REL, __HIP_MEMORY_SCOPE_AGENT);
        done = true;
      }
    }
    if (!done) {
      while (__hip_atomic_load(&bar[1], __ATOMIC_ACQUIRE, __HIP_MEMORY_SCOPE_AGENT) == g0)
        __builtin_amdgcn_s_sleep(2);
    }
    __threadfence();
    *bgen = g0 + 1u;
  }
  __syncthreads();
}

// ---------------- persistent kernel: weights LDS-resident, f32 acts split on the fly
// blocks 0..127: B-role (h1 update): cs = blk>>1 (8 cols), rh = blk&1 (128 rows)
// blocks 128..255: A-role (h0 update): cs, rh likewise; cs<8 blocks also do C-heads
// 8 waves: kh = wv>>2 (K half), mtq = wv&3 (32-row tile)
__global__ __launch_bounds__(512, 2) void persist_k(
    const float* __restrict__ z_temporal,
    const float* __restrict__ b_hh0,
    const float* __restrict__ b_ih1, const float* __restrict__ b_hh1,
    float* __restrict__ ws, HeadPtrs hp)
{
  __shared__ unsigned char smem[LDS_BYTES];
  const int blk = blockIdx.x, tid = threadIdx.x;
  const int wv = tid >> 6, l = tid & 63, lm = l & 15, lq = l >> 4;
  const int c16 = lm;                 // fragment col
  const int kh = wv >> 2, mtq = wv & 3;
  const bool roleB = (blk < 128);
  const int ba = roleB ? blk : blk - 128;
  const int cs = ba >> 1, rh = ba & 1;
  const int rowbase = rh * 128 + mtq * 32;
  const bool cge8 = (c16 >= 8);
  const int nofs = 512 + ((lq * 8 + (c16 & 7)) * 8);   // ushort offset within frag
  const bool desigC = (!roleB) && (cs < 8);
  const int cslC = cs & 3;
  const int rqC = rh * 2 + (cs >> 2);

  float* h0f = ws + H0F;
  float* h1f = ws + H1F;
  unsigned* bar = (unsigned*)(ws + BARO);
  unsigned bgen = 0;
  ushort_t* lw = (ushort_t*)smem;

  // ---- stage weights into LDS
  {
    const uint4* src = (const uint4*)((const ushort_t*)(ws + (roleB ? WGB : WGA)) +
                                      (size_t)cs * (roleB ? 73728 : 41472));
    uint4* d = (uint4*)smem;
    const int n16 = roleB ? 9216 : 5184;
    for (int i = tid; i < n16; i += 512) d[i] = src[i];
    if (desigC) {
      const uint4* srcC = (const uint4*)((const ushort_t*)(ws + WGC) + (size_t)cslC * 24576);
      uint4* dC = (uint4*)(smem + A_WC);
      for (int i = tid; i < 3072; i += 512) dC[i] = srcC[i];
    }
  }
  __syncthreads();

  float4* redRZ = (float4*)(smem + (roleB ? B_RZRED : A_RZRED));
  float4* redN1 = (float4*)(smem + (roleB ? B_NRED : A_NHRED));  // B: nh ; A: nh
  float4* redNI = (float4*)(smem + A_NIRED);
  float4* redC  = (float4*)(smem + A_CRED);
  const bf16x8 z8 = {};

  for (int s = 0; s <= 257; ++s) {
    const bool actB = roleB && s >= 1 && s <= 256;
    const bool actA = !roleB && s <= 255;
    const bool actC = desigC && s >= 2;

    f32x4 arz[2] = {}; f32x4 an[2] = {}; f32x4 ani[2] = {}; f32x4 ac = {};

    if (actB) {
      const float* act = (kh == 0) ? (h0f + (size_t)((s - 1) & 1) * 131072)
                                   : (h1f + (size_t)(s & 1) * 131072);
      #pragma unroll 2
      for (int kc = 0; kc < 16; ++kc) {
        const int kcg = kh * 16 + kc;
        const size_t fb = (size_t)kcg * 2304;
        bf16x8 wr0 = ldsb8(&lw[fb + l * 8]);
        bf16x8 wr1 = ldsb8(&lw[fb + 768 + l * 8]);
        bf16x8 wr2 = ldsb8(&lw[fb + 1536 + l * 8]);
        bf16x8 wn0 = cge8 ? z8 : ldsb8(&lw[fb + nofs]);
        bf16x8 wn1 = cge8 ? z8 : ldsb8(&lw[fb + 768 + nofs]);
        bf16x8 wn2 = cge8 ? z8 : ldsb8(&lw[fb + 1536 + nofs]);
        #pragma unroll
        for (int st = 0; st < 2; ++st) {
          const int row = rowbase + st * 16 + lm;
          const float* p = act + (size_t)row * 512 + kc * 32 + lq * 8;
          float v8[8]; *(float4*)v8 = *(const float4*)p; *(float4*)(v8 + 4) = *(const float4*)(p + 4);
          bf16x8 a0, a1, a2; split3v(v8, a0, a1, a2);
          arz[st] = mm6w(arz[st], a0, a1, a2, wr0, wr1, wr2);
          an[st]  = mm6w(an[st],  a0, a1, a2, wn0, wn1, wn2);
        }
      }
      if (kh == 1) {
        #pragma unroll
        for (int st = 0; st < 2; ++st) {
          const int sub = mtq * 2 + st;
          redRZ[sub * 64 + l] = float4{arz[st][0], arz[st][1], arz[st][2], arz[st][3]};
          if (!cge8) redN1[sub * 32 + lq * 8 + c16] = float4{an[st][0], an[st][1], an[st][2], an[st][3]};
        }
      }
    } else if (actA) {
      const float* act = h0f + (size_t)((s + 1) & 1) * 131072;
      const int k0 = kh * 9;
      #pragma unroll 2
      for (int kc = 0; kc < 9; ++kc) {
        const int kcg = k0 + kc;
        const size_t fb = (size_t)kcg * 2304;
        bf16x8 wr0 = ldsb8(&lw[fb + l * 8]);
        bf16x8 wr1 = ldsb8(&lw[fb + 768 + l * 8]);
        bf16x8 wr2 = ldsb8(&lw[fb + 1536 + l * 8]);
        bf16x8 wn0 = cge8 ? z8 : ldsb8(&lw[fb + nofs]);
        bf16x8 wn1 = cge8 ? z8 : ldsb8(&lw[fb + 768 + nofs]);
        bf16x8 wn2 = cge8 ? z8 : ldsb8(&lw[fb + 1536 + nofs]);
        const bool isz = (kcg >= 16);
        #pragma unroll
        for (int st = 0; st < 2; ++st) {
          const int row = rowbase + st * 16 + lm;
          const float* p = isz
            ? (z_temporal + ((size_t)row * 256 + s) * 64 + (kcg - 16) * 32 + lq * 8)
            : (act + (size_t)row * 512 + kcg * 32 + lq * 8);
          float v8[8]; *(float4*)v8 = *(const float4*)p; *(float4*)(v8 + 4) = *(const float4*)(p + 4);
          bf16x8 a0, a1, a2; split3v(v8, a0, a1, a2);
          arz[st] = mm6w(arz[st], a0, a1, a2, wr0, wr1, wr2);
          if (isz) ani[st] = mm6w(ani[st], a0, a1, a2, wn0, wn1, wn2);
          else     an[st]  = mm6w(an[st],  a0, a1, a2, wn0, wn1, wn2);
        }
      }
      if (kh == 1) {
        #pragma unroll
        for (int st = 0; st < 2; ++st) {
          const int sub = mtq * 2 + st;
          redRZ[sub * 64 + l] = float4{arz[st][0], arz[st][1], arz[st][2], arz[st][3]};
          if (!cge8) {
            redN1[sub * 32 + lq * 8 + c16] = float4{an[st][0], an[st][1], an[st][2], an[st][3]};
            redNI[sub * 32 + lq * 8 + c16] = float4{ani[st][0], ani[st][1], ani[st][2], ani[st][3]};
          }
        }
      }
    }

    if (actC && s <= 257) {
      const float* actC_ = h1f + (size_t)(s & 1) * 131072;
      const ushort_t* lwc = (const ushort_t*)(smem + A_WC);
      const int kb = kh * 8;
      #pragma unroll 2
      for (int kc = 0; kc < 8; ++kc) {
        const int kcg = kb + kc;
        const size_t fb = (size_t)kcg * 1536;
        bf16x8 w0 = ldsb8(&lwc[fb + l * 8]);
        bf16x8 w1 = ldsb8(&lwc[fb + 512 + l * 8]);
        bf16x8 w2 = ldsb8(&lwc[fb + 1024 + l * 8]);
        const int row = rqC * 64 + mtq * 16 + lm;
        const float* p = actC_ + (size_t)row * 512 + kcg * 32 + lq * 8;
        float v8[8]; *(float4*)v8 = *(const float4*)p; *(float4*)(v8 + 4) = *(const float4*)(p + 4);
        bf16x8 a0, a1, a2; split3v(v8, a0, a1, a2);
        ac = mm6w(ac, a0, a1, a2, w0, w1, w2);
      }
      if (kh == 1) redC[mtq * 64 + l] = float4{ac[0], ac[1], ac[2], ac[3]};
    }

    __syncthreads();

    // ---------- finalize (kh==0 waves) ----------
    if (actB && kh == 0) {
      const float* h1f_old = h1f + (size_t)(s & 1) * 131072;
      float* h1f_cur = h1f + (size_t)((s - 1) & 1) * 131072;
      #pragma unroll
      for (int st = 0; st < 2; ++st) {
        const int sub = mtq * 2 + st;
        float4 rd = redRZ[sub * 64 + l];
        f32x4 rzt = arz[st]; rzt[0] += rd.x; rzt[1] += rd.y; rzt[2] += rd.z; rzt[3] += rd.w;
        f32x4 zt;
        #pragma unroll
        for (int r = 0; r < 4; ++r) zt[r] = __shfl_xor(rzt[r], 8, 64);
        if (!cge8) {
          float4 nhv = redN1[sub * 32 + lq * 8 + c16];
          const int h = cs * 8 + c16;
          const float br = b_ih1[h] + b_hh1[h];
          const float bz = b_ih1[512 + h] + b_hh1[512 + h];
          const float bni = b_ih1[1024 + h], bnh = b_hh1[1024 + h];
          const float nh4[4] = {nhv.x, nhv.y, nhv.z, nhv.w};
          #pragma unroll
          for (int r = 0; r < 4; ++r) {
            const int row = rowbase + st * 16 + lq * 4 + r;
            const float rg = sigmoidf_(rzt[r] + br);
            const float zg = sigmoidf_(zt[r] + bz);
            const float n = tanhf((an[st][r] + bni) + rg * (nh4[r] + bnh));
            const float hold = h1f_old[(size_t)row * 512 + h];
            h1f_cur[(size_t)row * 512 + h] = (1.0f - zg) * n + zg * hold;
          }
        }
      }
    } else if (actA && kh == 0) {
      const float* h0f_old = h0f + (size_t)((s + 1) & 1) * 131072;
      float* h0f_cur = h0f + (size_t)(s & 1) * 131072;
      const float* acc0 = ws + ACC0;
      #pragma unroll
      for (int st = 0; st < 2; ++st) {
        const int sub = mtq * 2 + st;
        float4 rd = redRZ[sub * 64 + l];
        f32x4 rzt = arz[st]; rzt[0] += rd.x; rzt[1] += rd.y; rzt[2] += rd.z; rzt[3] += rd.w;
        f32x4 zt;
        #pragma unroll
        for (int r = 0; r < 4; ++r) zt[r] = __shfl_xor(rzt[r], 8, 64);
        if (!cge8) {
          float4 nhv = redN1[sub * 32 + lq * 8 + c16];
          float4 niv = redNI[sub * 32 + lq * 8 + c16];
          const int h = cs * 8 + c16;
          const float bnh = b_hh0[1024 + h];
          const float nh4[4] = {nhv.x, nhv.y, nhv.z, nhv.w};
          const float ni4[4] = {niv.x, niv.y, niv.z, niv.w};
          #pragma unroll
          for (int r = 0; r < 4; ++r) {
            const int row = rowbase + st * 16 + lq * 4 + r;
            const float* acr = acc0 + (size_t)row * 1536;
            const float rg = sigmoidf_(rzt[r] + acr[h] + b_hh0[h]);
            const float zg = sigmoidf_(zt[r] + acr[512 + h] + b_hh0[512 + h]);
            const float n = tanhf((ni4[r] + acr[1024 + h]) + rg * ((an[st][r] + nh4[r]) + bnh));
            const float hold = h0f_old[(size_t)row * 512 + h];
            h0f_cur[(size_t)row * 512 + h] = (1.0f - zg) * n + zg * hold;
          }
        }
      }
    }

    if (actC && kh == 0) {
      float4 rd = redC[mtq * 64 + l];
      f32x4 tot = ac; tot[0] += rd.x; tot[1] += rd.y; tot[2] += rd.z; tot[3] += rd.w;
      const int col = cslC * 16 + c16;
      if (col < 60) {
        const float bias = head_bias(hp, col);
        const int t = s - 2;
        float* lg = ws + LOGB;
        #pragma unroll
        for (int r = 0; r < 4; ++r) {
          const int row = rqC * 64 + mtq * 16 + lq * 4 + r;
          lg[((size_t)row * 256 + t) * 64 + col] = tot[r] + bias;
        }
      }
    }

    gridbar(bar, &bgen);
  }
}

// ---------------- static heads
__global__ __launch_bounds__(64) void static_heads_k(const float* __restrict__ sh_buf,
    const float* __restrict__ scont_w, const float* __restrict__ scont_b,
    const float* __restrict__ scat_w, const float* __restrict__ scat_b,
    float* __restrict__ out, unsigned ks0, unsigned ks1)
{
  __shared__ float hrow[512];
  __shared__ float xl[10];
  __shared__ float yv[10];
  __shared__ int argsh;
  int b = blockIdx.x, tid = threadIdx.x;
  const float* hr = sh_buf + (size_t)b * 512;
  for (int i = tid; i < 512; i += 64) hrow[i] = hr[i];
  __syncthreads();
  if (tid < 16) {
    float a = 0.f;
    const float* w = scont_w + (size_t)tid * 512;
    for (int k = 0; k < 512; ++k) a += hrow[k] * w[k];
    out[O_SCONT + (size_t)b * 16 + tid] = a + scont_b[tid];
  }
  if (tid < 10) {
    float a = 0.f;
    const float* w = scat_w + (size_t)tid * 512;
    for (int k = 0; k < 512; ++k) a += hrow[k] * w[k];
    a += scat_b[tid];
    float u = rng_u01(ks0, ks1, (unsigned)(b * 10 + tid));
    u = fmaxf(1e-9f, u + 1e-9f);
    float g = -logf(-logf(u));
    xl[tid] = a + g;
  }
  __syncthreads();
  if (tid == 0) {
    float m = xl[0];
    for (int c = 1; c < 10; ++c) m = fmaxf(m, xl[c]);
    float ssum = 0.f;
    for (int c = 0; c < 10; ++c) { yv[c] = expf(xl[c] - m); ssum += yv[c]; }
    int arg = 0; float best = -1.0f;
    for (int c = 0; c < 10; ++c) { yv[c] = yv[c] / ssum; if (yv[c] > best) { best = yv[c]; arg = c; } }
    argsh = arg;
  }
  __syncthreads();
  if (tid < 10) {
    float y = yv[tid];
    out[O_SCAT + (size_t)b * 10 + tid] = (tid == argsh) ? ((1.0f + y) - y) : 0.0f;
  }
}

// ---------------- final scans + sampling + emission
struct Keys { unsigned kv0, kv1, ki00, ki01, ki10, ki11, kc00, kc01, kc10, kc11; };

__global__ __launch_bounds__(256) void final_k(const float* __restrict__ ws, float* __restrict__ out, Keys ky)
{
  __shared__ float sh[256];
  __shared__ unsigned shu[256];
  int b = blockIdx.x, t = threadIdx.x;
  int idx = b * 256 + t;
  const float* lg = ws + LOGB + (size_t)idx * 64;
  float l0 = lg[0], l1 = lg[1], l34 = lg[34], l35 = lg[35];

  float dt = fmaxf(l0, 0.0f) + log1pf(expf(-fabsf(l0)));
  sh[t] = dt; __syncthreads();
  for (int off = 1; off < 256; off <<= 1) {
    float v = (t >= off) ? sh[t - off] : 0.0f;
    __syncthreads();
    sh[t] += v;
    __syncthreads();
  }
  float vt = sh[t];
  float denom = sh[255] + 1e-8f;
  out[O_VTIME + idx] = vt / denom;
  __syncthreads();

  float pv = sigmoidf_(l1);
  float uv = rng_u01(ky.kv0, ky.kv1, (unsigned)idx);
  shu[t] = (t == 0) ? 1u : (uv < pv ? 1u : 0u);
  __syncthreads();
  for (int off = 1; off < 256; off <<= 1) {
    unsigned v = (t >= off) ? shu[t - off] : 1u;
    __syncthreads();
    shu[t] &= v;
    __syncthreads();
  }
  float mask = (float)shu[t];
  out[O_VMASK + idx] = mask;
  __syncthreads();

  {
    float hz = sigmoidf_(l34);
    float u = rng_u01(ky.ki00, ky.ki01, (unsigned)idx);
    shu[t] = (u < hz) ? 1u : 0u;
    __syncthreads();
    for (int off = 1; off < 256; off <<= 1) {
      unsigned v = (t >= off) ? shu[t - off] : 0u;
      __syncthreads();
      shu[t] |= v;
      __syncthreads();
    }
    float st = (float)shu[t];
    out[O_IRR0 + (size_t)idx * 2]     = (1.0f - st) * mask;
    out[O_IRR0 + (size_t)idx * 2 + 1] = st * mask;
    __syncthreads();
  }
  {
    float hz = sigmoidf_(l35);
    float u = rng_u01(ky.ki10, ky.ki11, (unsigned)idx);
    shu[t] = (u < hz) ? 1u : 0u;
    __syncthreads();
    for (int off = 1; off < 256; off <<= 1) {
      unsigned v = (t >= off) ? shu[t - off] : 0u;
      __syncthreads();
      shu[t] |= v;
      __syncthreads();
    }
    float st = (float)shu[t];
    out[O_IRR1 + (size_t)idx * 2]     = (1.0f - st) * mask;
    out[O_IRR1 + (size_t)idx * 2 + 1] = st * mask;
  }

  #pragma unroll
  for (int c = 0; c < 32; ++c)
    out[O_TCONT + (size_t)idx * 32 + c] = lg[2 + c] * mask;

  {
    float x[8], y[8];
    float m = -1e30f;
    #pragma unroll
    for (int c = 0; c < 8; ++c) {
      float u = rng_u01(ky.kc00, ky.kc01, (unsigned)idx * 8u + c);
      u = fmaxf(1e-9f, u + 1e-9f);
      float g = -logf(-logf(u));
      x[c] = lg[36 + c] + g;
      m = fmaxf(m, x[c]);
    }
    float ssum = 0.f;
    #pragma unroll
    for (int c = 0; c < 8; ++c) { y[c] = expf(x[c] - m); ssum += y[c]; }
    int arg = 0; float best = -1.0f;
    #pragma unroll
    for (int c = 0; c < 8; ++c) { y[c] /= ssum; if (y[c] > best) { best = y[c]; arg = c; } }
    #pragma unroll
    for (int c = 0; c < 8; ++c)
      out[O_CAT0 + (size_t)idx * 8 + c] = (c == arg) ? ((1.0f + y[c]) - y[c]) * mask : 0.0f;
  }
  {
    float x[16], y[16];
    float m = -1e30f;
    #pragma unroll
    for (int c = 0; c < 16; ++c) {
      float u = rng_u01(ky.kc10, ky.kc11, (unsigned)idx * 16u + c);
      u = fmaxf(1e-9f, u + 1e-9f);
      float g = -logf(-logf(u));
      x[c] = lg[44 + c] + g;
      m = fmaxf(m, x[c]);
    }
    float ssum = 0.f;
    #pragma unroll
    for (int c = 0; c < 16; ++c) { y[c] = expf(x[c] - m); ssum += y[c]; }
    int arg = 0; float best = -1.0f;
    #pragma unroll
    for (int c = 0; c < 16; ++c) { y[c] /= ssum; if (y[c] > best) { best = y[c]; arg = c; } }
    #pragma unroll
    for (int c = 0; c < 16; ++c)
      out[O_CAT1 + (size_t)idx * 16 + c] = (c == arg) ? ((1.0f + y[c]) - y[c]) * mask : 0.0f;
  }
}

// ---------------- host entry
extern "C" void kernel_launch(void* const* d_in, const int* in_sizes, int n_in,
                              void* d_out, int out_size, void* d_ws, size_t ws_size,
                              hipStream_t stream)
{
  (void)in_sizes; (void)n_in; (void)out_size; (void)ws_size;
  const float* z_static   = (const float*)d_in[0];
  const float* z_temporal = (const float*)d_in[1];
  const float* fc1_w = (const float*)d_in[2];
  const float* fc1_b = (const float*)d_in[3];
  const float* fc2_w = (const float*)d_in[4];
  const float* fc2_b = (const float*)d_in[5];
  const float* w_ih0 = (const float*)d_in[6];
  const float* w_hh0 = (const float*)d_in[7];
  const float* b_ih0 = (const float*)d_in[8];
  const float* b_hh0 = (const float*)d_in[9];
  const float* w_ih1 = (const float*)d_in[10];
  const float* w_hh1 = (const float*)d_in[11];
  const float* b_ih1 = (const float*)d_in[12];
  const float* b_hh1 = (const float*)d_in[13];
  const float* time_w = (const float*)d_in[14];
  const float* time_b = (const float*)d_in[15];
  const float* visit_w = (const float*)d_in[16];
  const float* visit_b = (const float*)d_in[17];
  const float* tcont_w = (const float*)d_in[18];
  const float* tcont_b = (const float*)d_in[19];
  const float* irr0_w = (const float*)d_in[20];
  const float* irr0_b = (const float*)d_in[21];
  const float* irr1_w = (const float*)d_in[22];
  const float* irr1_b = (const float*)d_in[23];
  const float* cat0_w = (const float*)d_in[24];
  const float* cat0_b = (const float*)d_in[25];
  const float* cat1_w = (const float*)d_in[26];
  const float* cat1_b = (const float*)d_in[27];
  const float* scont_w = (const float*)d_in[28];
  const float* scont_b = (const float*)d_in[29];
  const float* scat_w = (const float*)d_in[30];
  const float* scat_b = (const float*)d_in[31];
  float* ws = (float*)d_ws;
  float* out = (float*)d_out;

  // static-path transposes (aliased into LOGB region, consumed pre-loop)
  transpose_k<<<dim3(4, 16), 256, 0, stream>>>(fc1_w, ws + FC1T, 512, 128, 128, 512);
  transpose_k<<<dim3(16, 16), 256, 0, stream>>>(fc2_w, ws + FC2T, 512, 512, 512, 512);
  transpose_k<<<dim3(16, 48), 256, 0, stream>>>(w_ih0 + 64, ws + WIS, 1536, 512, 576, 1536);
  hgather_k<<<64, 128, 0, stream>>>(time_w, visit_w, tcont_w, irr0_w, irr1_w, cat0_w, cat1_w, ws + WTH);

  // static path: static_h, acc0
  gemm_k<<<8 * 16, 128, 0, stream>>>(z_static, ws + FC1T, fc1_b, ws + HID, 256, 128, 512, 1);
  gemm_k<<<8 * 16, 128, 0, stream>>>(ws + HID, ws + FC2T, fc2_b, ws + SHH, 256, 512, 512, 0);
  gemm_k<<<8 * 48, 128, 0, stream>>>(ws + SHH, ws + WIS, b_ih0, ws + ACC0, 256, 512, 1536, 0);

  // arrange per-block LDS weight images
  arrB_k<<<(64 * 32 * 3 * 96 + 255) / 256, 256, 0, stream>>>(w_ih1, w_hh1, (ushort_t*)(ws + WGB));
  arrA_k<<<(64 * 18 * 3 * 96 + 255) / 256, 256, 0, stream>>>(w_hh0, w_ih0, (ushort_t*)(ws + WGA));
  arrC_k<<<(4 * 16 * 3 * 64 + 255) / 256, 256, 0, stream>>>(ws + WTH, (ushort_t*)(ws + WGC));

  // RNG keys: key(42) = (0,42); 6 children (partitionable fold-in)
  unsigned kk[6][2];
  for (int i = 0; i < 6; ++i) tf2x32(0u, 42u, 0u, (unsigned)i, &kk[i][0], &kk[i][1]);

  static_heads_k<<<256, 64, 0, stream>>>(ws + SHH, scont_w, scont_b, scat_w, scat_b, out,
                                         kk[5][0], kk[5][1]);

  // zero initial hidden states (parity 1) + barrier
  hipMemsetAsync((void*)(ws + H0F + 131072), 0, 131072 * sizeof(float), stream);
  hipMemsetAsync((void*)(ws + H1F + 131072), 0, 131072 * sizeof(float), stream);
  hipMemsetAsync((void*)(ws + BARO), 0, 64, stream);

  HeadPtrs hp{time_b, visit_b, tcont_b, irr0_b, irr1_b, cat0_b, cat1_b};
  persist_k<<<256, 512, 0, stream>>>(z_temporal, b_hh0, b_ih1, b_hh1, ws, hp);

  Keys ky{kk[0][0], kk[0][1], kk[1][0], kk[1][1], kk[2][0], kk[2][1],
          kk[3][0], kk[3][1], kk[4][0], kk[4][1]};
  final_k<<<256, 256, 0, stream>>>(ws, out, ky);
}

// Round 8
// 19783.267 us; speedup vs baseline: 1.0048x; 1.0048x over previous
//
#include <hip/hip_runtime.h>
#include <hip/hip_bf16.h>
#include <cstdint>
#include <cstddef>

typedef __bf16 bf16x8 __attribute__((ext_vector_type(8)));
typedef float f32x4 __attribute__((ext_vector_type(4)));
typedef unsigned short ushort_t;

// sizes: B=256, T=256, ZS=128, ZT=64, H=512, 3H=1536

// ---------------- workspace layout (float offsets)
static constexpr size_t ACC0 = 0;                 // [256][1536] f32 static xp0 (+b_ih0)
static constexpr size_t SHH  = 393216;            // [256][512] static_h
static constexpr size_t HID  = 524288;            // [256][512]
static constexpr size_t H0F  = 655360;            // [2][256][512] f32 ping-pong h0
static constexpr size_t H1F  = 917504;            // [2][256][512] f32 ping-pong h1
static constexpr size_t LOGB = 1179648;           // [256][256][64] f32 head logits
static constexpr size_t WTH  = 5373952;           // [512][64] f32 gathered head weights
static constexpr size_t WGB  = 5406720;           // 64 cs x 73728 ush  (B LDS images)
static constexpr size_t WGA  = 7766016;           // 64 cs x 41472 ush  (A LDS images)
static constexpr size_t WGC  = 9093120;           // 4 slices x 24576 ush (C LDS images)
static constexpr size_t BARO = 9142272;           // barrier (16 u32)
// pre-loop overlays in LOGB (consumed before persist writes LOGB)
static constexpr size_t FC1T = LOGB;
static constexpr size_t FC2T = LOGB + 65536;
static constexpr size_t WIS  = FC2T + 262144;

// ---------------- output layout (float offsets)
static constexpr size_t O_SCONT = 0;
static constexpr size_t O_SCAT  = 4096;
static constexpr size_t O_TCONT = 6656;
static constexpr size_t O_IRR0  = 2103808;
static constexpr size_t O_IRR1  = 2234880;
static constexpr size_t O_CAT0  = 2365952;
static constexpr size_t O_CAT1  = 2890240;
static constexpr size_t O_VMASK = 3938816;
static constexpr size_t O_VTIME = 4004352;

// ---------------- LDS layout (bytes), role-dependent
static constexpr int LDS_BYTES = 159744;
// B: W 0..147455 | redRZ 147456 (+8192) | redN 155648 (+4096)
static constexpr int B_RZRED = 147456;
static constexpr int B_NRED  = 155648;
// A: W 0..82943 | WC 82944 (+49152) | redRZ 132096 | redNH 140288 | redNI 144384 | redC 148480
static constexpr int A_WC    = 82944;
static constexpr int A_RZRED = 132096;
static constexpr int A_NHRED = 140288;
static constexpr int A_NIRED = 144384;
static constexpr int A_CRED  = 148480;

// ---------------- threefry2x32-20
__host__ __device__ inline void tf2x32(unsigned k0, unsigned k1, unsigned x0, unsigned x1,
                                       unsigned* o0, unsigned* o1) {
  unsigned ks2 = k0 ^ k1 ^ 0x1BD11BDAu;
#define TFR(r) { x0 += x1; x1 = (x1 << (r)) | (x1 >> (32 - (r))); x1 ^= x0; }
  x0 += k0; x1 += k1;
  TFR(13) TFR(15) TFR(26) TFR(6)
  x0 += k1; x1 += ks2 + 1u;
  TFR(17) TFR(29) TFR(16) TFR(24)
  x0 += ks2; x1 += k0 + 2u;
  TFR(13) TFR(15) TFR(26) TFR(6)
  x0 += k0; x1 += k1 + 3u;
  TFR(17) TFR(29) TFR(16) TFR(24)
  x0 += k1; x1 += ks2 + 4u;
  TFR(13) TFR(15) TFR(26) TFR(6)
  x0 += ks2; x1 += k0 + 5u;
#undef TFR
  *o0 = x0; *o1 = x1;
}

__device__ inline float rng_u01(unsigned k0, unsigned k1, unsigned idx) {
  unsigned o0, o1;
  tf2x32(k0, k1, 0u, idx, &o0, &o1);
  unsigned bits = o0 ^ o1;
  return __uint_as_float((bits >> 9) | 0x3f800000u) - 1.0f;
}

__device__ inline float sigmoidf_(float x) { return 1.0f / (1.0f + expf(-x)); }

// ---------------- tiled transpose
__global__ __launch_bounds__(256) void transpose_k(const float* __restrict__ src, float* __restrict__ dst,
                                                   int J, int K, int srcStride, int dstStride) {
  __shared__ float tile[32][33];
  int kb = blockIdx.x * 32, jb = blockIdx.y * 32;
  int tx = threadIdx.x & 31, ty = threadIdx.x >> 5;
  #pragma unroll
  for (int r = 0; r < 4; ++r) {
    int j = jb + ty + r * 8, k = kb + tx;
    if (j < J && k < K) tile[ty + r * 8][tx] = src[(size_t)j * srcStride + k];
  }
  __syncthreads();
  #pragma unroll
  for (int r = 0; r < 4; ++r) {
    int k = kb + ty + r * 8, j = jb + tx;
    if (k < K && j < J) dst[(size_t)k * dstStride + j] = tile[tx][ty + r * 8];
  }
}

// ---------------- gather head weights into wtH[512][64] (cols 60..63 zero)
__global__ void hgather_k(const float* __restrict__ time_w, const float* __restrict__ visit_w,
                          const float* __restrict__ tcont_w, const float* __restrict__ irr0_w,
                          const float* __restrict__ irr1_w, const float* __restrict__ cat0_w,
                          const float* __restrict__ cat1_w, float* __restrict__ wtH) {
  int c = blockIdx.x;
  if (c >= 60) {
    for (int k = threadIdx.x; k < 512; k += blockDim.x) wtH[(size_t)k * 64 + c] = 0.0f;
    return;
  }
  const float* src;
  if (c == 0) src = time_w;
  else if (c == 1) src = visit_w;
  else if (c < 34) src = tcont_w + (size_t)(c - 2) * 512;
  else if (c == 34) src = irr0_w;
  else if (c == 35) src = irr1_w;
  else if (c < 44) src = cat0_w + (size_t)(c - 36) * 512;
  else src = cat1_w + (size_t)(c - 44) * 512;
  for (int k = threadIdx.x; k < 512; k += blockDim.x) wtH[(size_t)k * 64 + c] = src[k];
}

// ---------------- fp32 GEMM (pre-loop static path)
__global__ __launch_bounds__(128) void gemm_k(const float* __restrict__ in, const float* __restrict__ wT,
                                              const float* __restrict__ bias, float* __restrict__ out,
                                              int M, int K, int J, int relu) {
  __shared__ float ibuf[64][34];
  __shared__ float wbuf[64][36];
  int jt = blockIdx.x % (J >> 5), mt = blockIdx.x / (J >> 5);
  int m0 = mt * 32, j0 = jt * 32;
  int tid = threadIdx.x;
  int mq = tid & 15, jq = tid >> 4;
  float acc[2][4] = {{0.f, 0.f, 0.f, 0.f}, {0.f, 0.f, 0.f, 0.f}};
  for (int kc = 0; kc < K; kc += 64) {
    __syncthreads();
    #pragma unroll
    for (int i = 0; i < 16; ++i) {
      int lin = i * 128 + tid;
      int k = lin & 63, m = lin >> 6;
      ibuf[k][m] = in[(size_t)(m0 + m) * K + kc + k];
    }
    #pragma unroll
    for (int i = 0; i < 16; ++i) {
      int lin = i * 128 + tid;
      int c = lin & 31, k = lin >> 5;
      wbuf[k][c] = wT[(size_t)(kc + k) * J + j0 + c];
    }
    __syncthreads();
    #pragma unroll 8
    for (int k = 0; k < 64; ++k) {
      float i0 = ibuf[k][2 * mq], i1 = ibuf[k][2 * mq + 1];
      const float4 w = *(const float4*)&wbuf[k][4 * jq];
      acc[0][0] += i0 * w.x; acc[0][1] += i0 * w.y; acc[0][2] += i0 * w.z; acc[0][3] += i0 * w.w;
      acc[1][0] += i1 * w.x; acc[1][1] += i1 * w.y; acc[1][2] += i1 * w.z; acc[1][3] += i1 * w.w;
    }
  }
  #pragma unroll
  for (int mi = 0; mi < 2; ++mi)
    #pragma unroll
    for (int ji = 0; ji < 4; ++ji) {
      int j = j0 + 4 * jq + ji;
      float v = acc[mi][ji] + bias[j];
      if (relu) v = fmaxf(v, 0.0f);
      out[(size_t)(m0 + 2 * mq + mi) * J + j] = v;
    }
}

// ---------------- split helpers
__device__ inline ushort_t split_pick(float v, int spl) {
  __bf16 t0 = (__bf16)v; float r1 = v - (float)t0;
  __bf16 t1 = (__bf16)r1; float r2 = r1 - (float)t1;
  __bf16 t2 = (__bf16)r2;
  __bf16 t = (spl == 0) ? t0 : ((spl == 1) ? t1 : t2);
  return __builtin_bit_cast(ushort_t, t);
}

__device__ inline void split3v(const float* v8, bf16x8& a0, bf16x8& a1, bf16x8& a2) {
  #pragma unroll
  for (int j = 0; j < 8; ++j) {
    float v = v8[j];
    __bf16 t0 = (__bf16)v; float r1 = v - (float)t0;
    __bf16 t1 = (__bf16)r1; float r2 = r1 - (float)t1;
    a0[j] = t0; a1[j] = t1; a2[j] = (__bf16)r2;
  }
}

// ---------------- arrange kernels: build per-block LDS weight images
// B image per cs (73728 ush): [kc 0..31][spl 0..2]{ rz-frag 512 ush | n-frag 256 ush }
// rz-frag elem(l,j): c=l&15, gate = c<8?r:z, hcol=cs*8+(c&7), k=kc*32+(l>>4)*8+j
// n-frag  elem(l2,j): lq=l2>>3, c=l2&7, hcol=cs*8+c, k=kc*32+lq*8+j (gate n)
__global__ __launch_bounds__(256) void arrB_k(const float* __restrict__ w_ih1,
                                              const float* __restrict__ w_hh1,
                                              ushort_t* __restrict__ dst) {
  int id = blockIdx.x * 256 + threadIdx.x;
  if (id >= 64 * 32 * 3 * 96) return;
  int u = id % 96; int r = id / 96;
  int spl = r % 3; r /= 3;
  int kc = r % 32; int cs = r / 32;
  size_t base = (size_t)cs * 73728 + (size_t)(kc * 3 + spl) * 768;
  if (u < 64) {
    int c = u & 15; int gate = (c < 8) ? 0 : 1; int hcol = cs * 8 + (c & 7);
    int grow = gate * 512 + hcol;
    #pragma unroll
    for (int j = 0; j < 8; ++j) {
      int k = kc * 32 + (u >> 4) * 8 + j;
      float v = (k < 512) ? w_ih1[(size_t)grow * 512 + k] : w_hh1[(size_t)grow * 512 + k - 512];
      dst[base + u * 8 + j] = split_pick(v, spl);
    }
  } else {
    int l2 = u - 64; int lq = l2 >> 3, c = l2 & 7; int grow = 1024 + cs * 8 + c;
    #pragma unroll
    for (int j = 0; j < 8; ++j) {
      int k = kc * 32 + lq * 8 + j;
      float v = (k < 512) ? w_ih1[(size_t)grow * 512 + k] : w_hh1[(size_t)grow * 512 + k - 512];
      dst[base + 512 + l2 * 8 + j] = split_pick(v, spl);
    }
  }
}

// A image per cs (41472 ush): [kc 0..17][spl]{ rz 512 | n 256 }; K: 0..511=w_hh0, 512..575=w_ih0[:, :64]
__global__ __launch_bounds__(256) void arrA_k(const float* __restrict__ w_hh0,
                                              const float* __restrict__ w_ih0,
                                              ushort_t* __restrict__ dst) {
  int id = blockIdx.x * 256 + threadIdx.x;
  if (id >= 64 * 18 * 3 * 96) return;
  int u = id % 96; int r = id / 96;
  int spl = r % 3; r /= 3;
  int kc = r % 18; int cs = r / 18;
  size_t base = (size_t)cs * 41472 + (size_t)(kc * 3 + spl) * 768;
  if (u < 64) {
    int c = u & 15; int gate = (c < 8) ? 0 : 1; int hcol = cs * 8 + (c & 7);
    int grow = gate * 512 + hcol;
    #pragma unroll
    for (int j = 0; j < 8; ++j) {
      int k = kc * 32 + (u >> 4) * 8 + j;
      float v = (k < 512) ? w_hh0[(size_t)grow * 512 + k] : w_ih0[(size_t)grow * 576 + k - 512];
      dst[base + u * 8 + j] = split_pick(v, spl);
    }
  } else {
    int l2 = u - 64; int lq = l2 >> 3, c = l2 & 7; int grow = 1024 + cs * 8 + c;
    #pragma unroll
    for (int j = 0; j < 8; ++j) {
      int k = kc * 32 + lq * 8 + j;
      float v = (k < 512) ? w_hh0[(size_t)grow * 512 + k] : w_ih0[(size_t)grow * 576 + k - 512];
      dst[base + 512 + l2 * 8 + j] = split_pick(v, spl);
    }
  }
}

// C image per slice (24576 ush): [kc 0..15][spl][full 16-col frag 512 ush]
__global__ __launch_bounds__(256) void arrC_k(const float* __restrict__ wtH,
                                              ushort_t* __restrict__ dst) {
  int id = blockIdx.x * 256 + threadIdx.x;
  if (id >= 4 * 16 * 3 * 64) return;
  int l = id & 63; int r = id >> 6;
  int spl = r % 3; r /= 3;
  int kc = r % 16; int sl = r / 16;
  size_t base = (size_t)sl * 24576 + (size_t)(kc * 3 + spl) * 512;
  int c = sl * 16 + (l & 15);
  #pragma unroll
  for (int j = 0; j < 8; ++j) {
    int k = kc * 32 + (l >> 4) * 8 + j;
    dst[base + l * 8 + j] = split_pick(wtH[(size_t)k * 64 + c], spl);
  }
}

// ---------------- MFMA helpers
#define MFMA_(A, W, C) __builtin_amdgcn_mfma_f32_16x16x32_bf16((A), (W), (C), 0, 0, 0)

__device__ inline f32x4 mm6w(f32x4 acc, bf16x8 a0, bf16x8 a1, bf16x8 a2,
                             bf16x8 w0, bf16x8 w1, bf16x8 w2) {
  acc = MFMA_(a0, w0, acc); acc = MFMA_(a0, w1, acc); acc = MFMA_(a1, w0, acc);
  acc = MFMA_(a1, w1, acc); acc = MFMA_(a0, w2, acc); acc = MFMA_(a2, w0, acc);
  return acc;
}

__device__ inline bf16x8 ldsb8(const void* p) { return *(const bf16x8*)p; }

struct HeadPtrs {
  const float *time_b, *visit_b, *tcont_b, *irr0_b, *irr1_b, *cat0_b, *cat1_b;
};

__device__ inline float head_bias(const HeadPtrs& hp, int c) {
  if (c == 0) return hp.time_b[0];
  if (c == 1) return hp.visit_b[0];
  if (c < 34) return hp.tcont_b[c - 2];
  if (c == 34) return hp.irr0_b[0];
  if (c == 35) return hp.irr1_b[0];
  if (c < 44) return hp.cat0_b[c - 36];
  return hp.cat1_b[c - 44];
}

// ---------------- two-level grid barrier (256 blocks, 8 classes of 32)
__device__ inline void gridbar(unsigned* bar, unsigned* bgen) {
  __syncthreads();
  if (threadIdx.x == 0) {
    __threadfence();
    const unsigned g0 = *bgen;
    const int cls = blockIdx.x & 7;
    unsigned t = __hip_atomic_fetch_add(&bar[8 + cls], 1u, __ATOMIC_ACQ_REL, __HIP_MEMORY_SCOPE_AGENT);
    bool done = false;
    if (t == 31u) {
      unsigned t2 = __hip_atomic_fetch_add(&bar[0], 1u, __ATOMIC_ACQ_REL, __HIP_MEMORY_SCOPE_AGENT);
      if (t2 == 7u) {
        #pragma unroll
        for (int x = 0; x < 8; ++x)
          __hip_atomic_store(&bar[8 + x], 0u, __ATOMIC_RELAXED, __HIP_MEMORY_SCOPE_AGENT);
        __hip_atomic_store(&bar[0], 0u, __ATOMIC_RELAXED, __HIP_MEMORY_SCOPE_AGENT);
        __threadfence();
        __hip_atomic_fetch_add(&bar[1], 1u, __ATOMIC_ACQ_REL, __HIP_MEMORY_SCOPE_AGENT);
        done = true;
      }
    }
    if (!done) {
      while (__hip_atomic_load(&bar[1], __ATOMIC_ACQUIRE, __HIP_MEMORY_SCOPE_AGENT) == g0)
        __builtin_amdgcn_s_sleep(2);
    }
    __threadfence();
    *bgen = g0 + 1u;
  }
  __syncthreads();
}

// ---------------- persistent kernel: weights LDS-resident, f32 acts split on the fly
// blocks 0..127: B-role (h1 update): cs = blk>>1 (8 cols), rh = blk&1 (128 rows)
// blocks 128..255: A-role (h0 update): cs, rh likewise; cs<8 blocks also do C-heads
// 8 waves: kh = wv>>2 (K half), mtq = wv&3 (32-row tile)
__global__ __launch_bounds__(512, 2) void persist_k(
    const float* __restrict__ z_temporal,
    const float* __restrict__ b_hh0,
    const float* __restrict__ b_ih1, const float* __restrict__ b_hh1,
    float* __restrict__ ws, HeadPtrs hp)
{
  __shared__ unsigned char smem[LDS_BYTES];
  const int blk = blockIdx.x, tid = threadIdx.x;
  const int wv = tid >> 6, l = tid & 63, lm = l & 15, lq = l >> 4;
  const int c16 = lm;                 // fragment col
  const int kh = wv >> 2, mtq = wv & 3;
  const bool roleB = (blk < 128);
  const int ba = roleB ? blk : blk - 128;
  const int cs = ba >> 1, rh = ba & 1;
  const int rowbase = rh * 128 + mtq * 32;
  const bool cge8 = (c16 >= 8);
  const int nofs = 512 + ((lq * 8 + (c16 & 7)) * 8);   // ushort offset within frag
  const bool desigC = (!roleB) && (cs < 8);
  const int cslC = cs & 3;
  const int rqC = rh * 2 + (cs >> 2);

  float* h0f = ws + H0F;
  float* h1f = ws + H1F;
  unsigned* bar = (unsigned*)(ws + BARO);
  unsigned bgen = 0;
  ushort_t* lw = (ushort_t*)smem;

  // ---- stage weights into LDS
  {
    const uint4* src = (const uint4*)((const ushort_t*)(ws + (roleB ? WGB : WGA)) +
                                      (size_t)cs * (roleB ? 73728 : 41472));
    uint4* d = (uint4*)smem;
    const int n16 = roleB ? 9216 : 5184;
    for (int i = tid; i < n16; i += 512) d[i] = src[i];
    if (desigC) {
      const uint4* srcC = (const uint4*)((const ushort_t*)(ws + WGC) + (size_t)cslC * 24576);
      uint4* dC = (uint4*)(smem + A_WC);
      for (int i = tid; i < 3072; i += 512) dC[i] = srcC[i];
    }
  }
  __syncthreads();

  float4* redRZ = (float4*)(smem + (roleB ? B_RZRED : A_RZRED));
  float4* redN1 = (float4*)(smem + (roleB ? B_NRED : A_NHRED));  // B: nh ; A: nh
  float4* redNI = (float4*)(smem + A_NIRED);
  float4* redC  = (float4*)(smem + A_CRED);
  const bf16x8 z8 = {};

  for (int s = 0; s <= 257; ++s) {
    const bool actB = roleB && s >= 1 && s <= 256;
    const bool actA = !roleB && s <= 255;
    const bool actC = desigC && s >= 2;

    f32x4 arz[2] = {}; f32x4 an[2] = {}; f32x4 ani[2] = {}; f32x4 ac = {};

    if (actB) {
      const float* act = (kh == 0) ? (h0f + (size_t)((s - 1) & 1) * 131072)
                                   : (h1f + (size_t)(s & 1) * 131072);
      #pragma unroll 2
      for (int kc = 0; kc < 16; ++kc) {
        const int kcg = kh * 16 + kc;
        const size_t fb = (size_t)kcg * 2304;
        bf16x8 wr0 = ldsb8(&lw[fb + l * 8]);
        bf16x8 wr1 = ldsb8(&lw[fb + 768 + l * 8]);
        bf16x8 wr2 = ldsb8(&lw[fb + 1536 + l * 8]);
        bf16x8 wn0 = cge8 ? z8 : ldsb8(&lw[fb + nofs]);
        bf16x8 wn1 = cge8 ? z8 : ldsb8(&lw[fb + 768 + nofs]);
        bf16x8 wn2 = cge8 ? z8 : ldsb8(&lw[fb + 1536 + nofs]);
        #pragma unroll
        for (int st = 0; st < 2; ++st) {
          const int row = rowbase + st * 16 + lm;
          const float* p = act + (size_t)row * 512 + kc * 32 + lq * 8;
          float v8[8]; *(float4*)v8 = *(const float4*)p; *(float4*)(v8 + 4) = *(const float4*)(p + 4);
          bf16x8 a0, a1, a2; split3v(v8, a0, a1, a2);
          arz[st] = mm6w(arz[st], a0, a1, a2, wr0, wr1, wr2);
          an[st]  = mm6w(an[st],  a0, a1, a2, wn0, wn1, wn2);
        }
      }
      if (kh == 1) {
        #pragma unroll
        for (int st = 0; st < 2; ++st) {
          const int sub = mtq * 2 + st;
          redRZ[sub * 64 + l] = float4{arz[st][0], arz[st][1], arz[st][2], arz[st][3]};
          if (!cge8) redN1[sub * 32 + lq * 8 + c16] = float4{an[st][0], an[st][1], an[st][2], an[st][3]};
        }
      }
    } else if (actA) {
      const float* act = h0f + (size_t)((s + 1) & 1) * 131072;
      const int k0 = kh * 9;
      #pragma unroll 2
      for (int kc = 0; kc < 9; ++kc) {
        const int kcg = k0 + kc;
        const size_t fb = (size_t)kcg * 2304;
        bf16x8 wr0 = ldsb8(&lw[fb + l * 8]);
        bf16x8 wr1 = ldsb8(&lw[fb + 768 + l * 8]);
        bf16x8 wr2 = ldsb8(&lw[fb + 1536 + l * 8]);
        bf16x8 wn0 = cge8 ? z8 : ldsb8(&lw[fb + nofs]);
        bf16x8 wn1 = cge8 ? z8 : ldsb8(&lw[fb + 768 + nofs]);
        bf16x8 wn2 = cge8 ? z8 : ldsb8(&lw[fb + 1536 + nofs]);
        const bool isz = (kcg >= 16);
        #pragma unroll
        for (int st = 0; st < 2; ++st) {
          const int row = rowbase + st * 16 + lm;
          const float* p = isz
            ? (z_temporal + ((size_t)row * 256 + s) * 64 + (kcg - 16) * 32 + lq * 8)
            : (act + (size_t)row * 512 + kcg * 32 + lq * 8);
          float v8[8]; *(float4*)v8 = *(const float4*)p; *(float4*)(v8 + 4) = *(const float4*)(p + 4);
          bf16x8 a0, a1, a2; split3v(v8, a0, a1, a2);
          arz[st] = mm6w(arz[st], a0, a1, a2, wr0, wr1, wr2);
          if (isz) ani[st] = mm6w(ani[st], a0, a1, a2, wn0, wn1, wn2);
          else     an[st]  = mm6w(an[st],  a0, a1, a2, wn0, wn1, wn2);
        }
      }
      if (kh == 1) {
        #pragma unroll
        for (int st = 0; st < 2; ++st) {
          const int sub = mtq * 2 + st;
          redRZ[sub * 64 + l] = float4{arz[st][0], arz[st][1], arz[st][2], arz[st][3]};
          if (!cge8) {
            redN1[sub * 32 + lq * 8 + c16] = float4{an[st][0], an[st][1], an[st][2], an[st][3]};
            redNI[sub * 32 + lq * 8 + c16] = float4{ani[st][0], ani[st][1], ani[st][2], ani[st][3]};
          }
        }
      }
    }

    if (actC && s <= 257) {
      const float* actC_ = h1f + (size_t)(s & 1) * 131072;
      const ushort_t* lwc = (const ushort_t*)(smem + A_WC);
      const int kb = kh * 8;
      #pragma unroll 2
      for (int kc = 0; kc < 8; ++kc) {
        const int kcg = kb + kc;
        const size_t fb = (size_t)kcg * 1536;
        bf16x8 w0 = ldsb8(&lwc[fb + l * 8]);
        bf16x8 w1 = ldsb8(&lwc[fb + 512 + l * 8]);
        bf16x8 w2 = ldsb8(&lwc[fb + 1024 + l * 8]);
        const int row = rqC * 64 + mtq * 16 + lm;
        const float* p = actC_ + (size_t)row * 512 + kcg * 32 + lq * 8;
        float v8[8]; *(float4*)v8 = *(const float4*)p; *(float4*)(v8 + 4) = *(const float4*)(p + 4);
        bf16x8 a0, a1, a2; split3v(v8, a0, a1, a2);
        ac = mm6w(ac, a0, a1, a2, w0, w1, w2);
      }
      if (kh == 1) redC[mtq * 64 + l] = float4{ac[0], ac[1], ac[2], ac[3]};
    }

    __syncthreads();

    // ---------- finalize (kh==0 waves) ----------
    if (actB && kh == 0) {
      const float* h1f_old = h1f + (size_t)(s & 1) * 131072;
      float* h1f_cur = h1f + (size_t)((s - 1) & 1) * 131072;
      #pragma unroll
      for (int st = 0; st < 2; ++st) {
        const int sub = mtq * 2 + st;
        float4 rd = redRZ[sub * 64 + l];
        f32x4 rzt = arz[st]; rzt[0] += rd.x; rzt[1] += rd.y; rzt[2] += rd.z; rzt[3] += rd.w;
        f32x4 zt;
        #pragma unroll
        for (int r = 0; r < 4; ++r) zt[r] = __shfl_xor(rzt[r], 8, 64);
        if (!cge8) {
          float4 nhv = redN1[sub * 32 + lq * 8 + c16];
          const int h = cs * 8 + c16;
          const float br = b_ih1[h] + b_hh1[h];
          const float bz = b_ih1[512 + h] + b_hh1[512 + h];
          const float bni = b_ih1[1024 + h], bnh = b_hh1[1024 + h];
          const float nh4[4] = {nhv.x, nhv.y, nhv.z, nhv.w};
          #pragma unroll
          for (int r = 0; r < 4; ++r) {
            const int row = rowbase + st * 16 + lq * 4 + r;
            const float rg = sigmoidf_(rzt[r] + br);
            const float zg = sigmoidf_(zt[r] + bz);
            const float n = tanhf((an[st][r] + bni) + rg * (nh4[r] + bnh));
            const float hold = h1f_old[(size_t)row * 512 + h];
            h1f_cur[(size_t)row * 512 + h] = (1.0f - zg) * n + zg * hold;
          }
        }
      }
    } else if (actA && kh == 0) {
      const float* h0f_old = h0f + (size_t)((s + 1) & 1) * 131072;
      float* h0f_cur = h0f + (size_t)(s & 1) * 131072;
      const float* acc0 = ws + ACC0;
      #pragma unroll
      for (int st = 0; st < 2; ++st) {
        const int sub = mtq * 2 + st;
        float4 rd = redRZ[sub * 64 + l];
        f32x4 rzt = arz[st]; rzt[0] += rd.x; rzt[1] += rd.y; rzt[2] += rd.z; rzt[3] += rd.w;
        f32x4 zt;
        #pragma unroll
        for (int r = 0; r < 4; ++r) zt[r] = __shfl_xor(rzt[r], 8, 64);
        if (!cge8) {
          float4 nhv = redN1[sub * 32 + lq * 8 + c16];
          float4 niv = redNI[sub * 32 + lq * 8 + c16];
          const int h = cs * 8 + c16;
          const float bnh = b_hh0[1024 + h];
          const float nh4[4] = {nhv.x, nhv.y, nhv.z, nhv.w};
          const float ni4[4] = {niv.x, niv.y, niv.z, niv.w};
          #pragma unroll
          for (int r = 0; r < 4; ++r) {
            const int row = rowbase + st * 16 + lq * 4 + r;
            const float* acr = acc0 + (size_t)row * 1536;
            const float rg = sigmoidf_(rzt[r] + acr[h] + b_hh0[h]);
            const float zg = sigmoidf_(zt[r] + acr[512 + h] + b_hh0[512 + h]);
            const float n = tanhf((ni4[r] + acr[1024 + h]) + rg * ((an[st][r] + nh4[r]) + bnh));
            const float hold = h0f_old[(size_t)row * 512 + h];
            h0f_cur[(size_t)row * 512 + h] = (1.0f - zg) * n + zg * hold;
          }
        }
      }
    }

    if (actC && kh == 0) {
      float4 rd = redC[mtq * 64 + l];
      f32x4 tot = ac; tot[0] += rd.x; tot[1] += rd.y; tot[2] += rd.z; tot[3] += rd.w;
      const int col = cslC * 16 + c16;
      if (col < 60) {
        const float bias = head_bias(hp, col);
        const int t = s - 2;
        float* lg = ws + LOGB;
        #pragma unroll
        for (int r = 0; r < 4; ++r) {
          const int row = rqC * 64 + mtq * 16 + lq * 4 + r;
          lg[((size_t)row * 256 + t) * 64 + col] = tot[r] + bias;
        }
      }
    }

    gridbar(bar, &bgen);
  }
}

// ---------------- static heads
__global__ __launch_bounds__(64) void static_heads_k(const float* __restrict__ sh_buf,
    const float* __restrict__ scont_w, const float* __restrict__ scont_b,
    const float* __restrict__ scat_w, const float* __restrict__ scat_b,
    float* __restrict__ out, unsigned ks0, unsigned ks1)
{
  __shared__ float hrow[512];
  __shared__ float xl[10];
  __shared__ float yv[10];
  __shared__ int argsh;
  int b = blockIdx.x, tid = threadIdx.x;
  const float* hr = sh_buf + (size_t)b * 512;
  for (int i = tid; i < 512; i += 64) hrow[i] = hr[i];
  __syncthreads();
  if (tid < 16) {
    float a = 0.f;
    const float* w = scont_w + (size_t)tid * 512;
    for (int k = 0; k < 512; ++k) a += hrow[k] * w[k];
    out[O_SCONT + (size_t)b * 16 + tid] = a + scont_b[tid];
  }
  if (tid < 10) {
    float a = 0.f;
    const float* w = scat_w + (size_t)tid * 512;
    for (int k = 0; k < 512; ++k) a += hrow[k] * w[k];
    a += scat_b[tid];
    float u = rng_u01(ks0, ks1, (unsigned)(b * 10 + tid));
    u = fmaxf(1e-9f, u + 1e-9f);
    float g = -logf(-logf(u));
    xl[tid] = a + g;
  }
  __syncthreads();
  if (tid == 0) {
    float m = xl[0];
    for (int c = 1; c < 10; ++c) m = fmaxf(m, xl[c]);
    float ssum = 0.f;
    for (int c = 0; c < 10; ++c) { yv[c] = expf(xl[c] - m); ssum += yv[c]; }
    int arg = 0; float best = -1.0f;
    for (int c = 0; c < 10; ++c) { yv[c] = yv[c] / ssum; if (yv[c] > best) { best = yv[c]; arg = c; } }
    argsh = arg;
  }
  __syncthreads();
  if (tid < 10) {
    float y = yv[tid];
    out[O_SCAT + (size_t)b * 10 + tid] = (tid == argsh) ? ((1.0f + y) - y) : 0.0f;
  }
}

// ---------------- final scans + sampling + emission
struct Keys { unsigned kv0, kv1, ki00, ki01, ki10, ki11, kc00, kc01, kc10, kc11; };

__global__ __launch_bounds__(256) void final_k(const float* __restrict__ ws, float* __restrict__ out, Keys ky)
{
  __shared__ float sh[256];
  __shared__ unsigned shu[256];
  int b = blockIdx.x, t = threadIdx.x;
  int idx = b * 256 + t;
  const float* lg = ws + LOGB + (size_t)idx * 64;
  float l0 = lg[0], l1 = lg[1], l34 = lg[34], l35 = lg[35];

  float dt = fmaxf(l0, 0.0f) + log1pf(expf(-fabsf(l0)));
  sh[t] = dt; __syncthreads();
  for (int off = 1; off < 256; off <<= 1) {
    float v = (t >= off) ? sh[t - off] : 0.0f;
    __syncthreads();
    sh[t] += v;
    __syncthreads();
  }
  float vt = sh[t];
  float denom = sh[255] + 1e-8f;
  out[O_VTIME + idx] = vt / denom;
  __syncthreads();

  float pv = sigmoidf_(l1);
  float uv = rng_u01(ky.kv0, ky.kv1, (unsigned)idx);
  shu[t] = (t == 0) ? 1u : (uv < pv ? 1u : 0u);
  __syncthreads();
  for (int off = 1; off < 256; off <<= 1) {
    unsigned v = (t >= off) ? shu[t - off] : 1u;
    __syncthreads();
    shu[t] &= v;
    __syncthreads();
  }
  float mask = (float)shu[t];
  out[O_VMASK + idx] = mask;
  __syncthreads();

  {
    float hz = sigmoidf_(l34);
    float u = rng_u01(ky.ki00, ky.ki01, (unsigned)idx);
    shu[t] = (u < hz) ? 1u : 0u;
    __syncthreads();
    for (int off = 1; off < 256; off <<= 1) {
      unsigned v = (t >= off) ? shu[t - off] : 0u;
      __syncthreads();
      shu[t] |= v;
      __syncthreads();
    }
    float st = (float)shu[t];
    out[O_IRR0 + (size_t)idx * 2]     = (1.0f - st) * mask;
    out[O_IRR0 + (size_t)idx * 2 + 1] = st * mask;
    __syncthreads();
  }
  {
    float hz = sigmoidf_(l35);
    float u = rng_u01(ky.ki10, ky.ki11, (unsigned)idx);
    shu[t] = (u < hz) ? 1u : 0u;
    __syncthreads();
    for (int off = 1; off < 256; off <<= 1) {
      unsigned v = (t >= off) ? shu[t - off] : 0u;
      __syncthreads();
      shu[t] |= v;
      __syncthreads();
    }
    float st = (float)shu[t];
    out[O_IRR1 + (size_t)idx * 2]     = (1.0f - st) * mask;
    out[O_IRR1 + (size_t)idx * 2 + 1] = st * mask;
  }

  #pragma unroll
  for (int c = 0; c < 32; ++c)
    out[O_TCONT + (size_t)idx * 32 + c] = lg[2 + c] * mask;

  {
    float x[8], y[8];
    float m = -1e30f;
    #pragma unroll
    for (int c = 0; c < 8; ++c) {
      float u = rng_u01(ky.kc00, ky.kc01, (unsigned)idx * 8u + c);
      u = fmaxf(1e-9f, u + 1e-9f);
      float g = -logf(-logf(u));
      x[c] = lg[36 + c] + g;
      m = fmaxf(m, x[c]);
    }
    float ssum = 0.f;
    #pragma unroll
    for (int c = 0; c < 8; ++c) { y[c] = expf(x[c] - m); ssum += y[c]; }
    int arg = 0; float best = -1.0f;
    #pragma unroll
    for (int c = 0; c < 8; ++c) { y[c] /= ssum; if (y[c] > best) { best = y[c]; arg = c; } }
    #pragma unroll
    for (int c = 0; c < 8; ++c)
      out[O_CAT0 + (size_t)idx * 8 + c] = (c == arg) ? ((1.0f + y[c]) - y[c]) * mask : 0.0f;
  }
  {
    float x[16], y[16];
    float m = -1e30f;
    #pragma unroll
    for (int c = 0; c < 16; ++c) {
      float u = rng_u01(ky.kc10, ky.kc11, (unsigned)idx * 16u + c);
      u = fmaxf(1e-9f, u + 1e-9f);
      float g = -logf(-logf(u));
      x[c] = lg[44 + c] + g;
      m = fmaxf(m, x[c]);
    }
    float ssum = 0.f;
    #pragma unroll
    for (int c = 0; c < 16; ++c) { y[c] = expf(x[c] - m); ssum += y[c]; }
    int arg = 0; float best = -1.0f;
    #pragma unroll
    for (int c = 0; c < 16; ++c) { y[c] /= ssum; if (y[c] > best) { best = y[c]; arg = c; } }
    #pragma unroll
    for (int c = 0; c < 16; ++c)
      out[O_CAT1 + (size_t)idx * 16 + c] = (c == arg) ? ((1.0f + y[c]) - y[c]) * mask : 0.0f;
  }
}

// ---------------- host entry
extern "C" void kernel_launch(void* const* d_in, const int* in_sizes, int n_in,
                              void* d_out, int out_size, void* d_ws, size_t ws_size,
                              hipStream_t stream)
{
  (void)in_sizes; (void)n_in; (void)out_size; (void)ws_size;
  const float* z_static   = (const float*)d_in[0];
  const float* z_temporal = (const float*)d_in[1];
  const float* fc1_w = (const float*)d_in[2];
  const float* fc1_b = (const float*)d_in[3];
  const float* fc2_w = (const float*)d_in[4];
  const float* fc2_b = (const float*)d_in[5];
  const float* w_ih0 = (const float*)d_in[6];
  const float* w_hh0 = (const float*)d_in[7];
  const float* b_ih0 = (const float*)d_in[8];
  const float* b_hh0 = (const float*)d_in[9];
  const float* w_ih1 = (const float*)d_in[10];
  const float* w_hh1 = (const float*)d_in[11];
  const float* b_ih1 = (const float*)d_in[12];
  const float* b_hh1 = (const float*)d_in[13];
  const float* time_w = (const float*)d_in[14];
  const float* time_b = (const float*)d_in[15];
  const float* visit_w = (const float*)d_in[16];
  const float* visit_b = (const float*)d_in[17];
  const float* tcont_w = (const float*)d_in[18];
  const float* tcont_b = (const float*)d_in[19];
  const float* irr0_w = (const float*)d_in[20];
  const float* irr0_b = (const float*)d_in[21];
  const float* irr1_w = (const float*)d_in[22];
  const float* irr1_b = (const float*)d_in[23];
  const float* cat0_w = (const float*)d_in[24];
  const float* cat0_b = (const float*)d_in[25];
  const float* cat1_w = (const float*)d_in[26];
  const float* cat1_b = (const float*)d_in[27];
  const float* scont_w = (const float*)d_in[28];
  const float* scont_b = (const float*)d_in[29];
  const float* scat_w = (const float*)d_in[30];
  const float* scat_b = (const float*)d_in[31];
  float* ws = (float*)d_ws;
  float* out = (float*)d_out;

  // static-path transposes (aliased into LOGB region, consumed pre-loop)
  transpose_k<<<dim3(4, 16), 256, 0, stream>>>(fc1_w, ws + FC1T, 512, 128, 128, 512);
  transpose_k<<<dim3(16, 16), 256, 0, stream>>>(fc2_w, ws + FC2T, 512, 512, 512, 512);
  transpose_k<<<dim3(16, 48), 256, 0, stream>>>(w_ih0 + 64, ws + WIS, 1536, 512, 576, 1536);
  hgather_k<<<64, 128, 0, stream>>>(time_w, visit_w, tcont_w, irr0_w, irr1_w, cat0_w, cat1_w, ws + WTH);

  // static path: static_h, acc0
  gemm_k<<<8 * 16, 128, 0, stream>>>(z_static, ws + FC1T, fc1_b, ws + HID, 256, 128, 512, 1);
  gemm_k<<<8 * 16, 128, 0, stream>>>(ws + HID, ws + FC2T, fc2_b, ws + SHH, 256, 512, 512, 0);
  gemm_k<<<8 * 48, 128, 0, stream>>>(ws + SHH, ws + WIS, b_ih0, ws + ACC0, 256, 512, 1536, 0);

  // arrange per-block LDS weight images
  arrB_k<<<(64 * 32 * 3 * 96 + 255) / 256, 256, 0, stream>>>(w_ih1, w_hh1, (ushort_t*)(ws + WGB));
  arrA_k<<<(64 * 18 * 3 * 96 + 255) / 256, 256, 0, stream>>>(w_hh0, w_ih0, (ushort_t*)(ws + WGA));
  arrC_k<<<(4 * 16 * 3 * 64 + 255) / 256, 256, 0, stream>>>(ws + WTH, (ushort_t*)(ws + WGC));

  // RNG keys: key(42) = (0,42); 6 children (partitionable fold-in)
  unsigned kk[6][2];
  for (int i = 0; i < 6; ++i) tf2x32(0u, 42u, 0u, (unsigned)i, &kk[i][0], &kk[i][1]);

  static_heads_k<<<256, 64, 0, stream>>>(ws + SHH, scont_w, scont_b, scat_w, scat_b, out,
                                         kk[5][0], kk[5][1]);

  // zero initial hidden states (parity 1) + barrier
  hipMemsetAsync((void*)(ws + H0F + 131072), 0, 131072 * sizeof(float), stream);
  hipMemsetAsync((void*)(ws + H1F + 131072), 0, 131072 * sizeof(float), stream);
  hipMemsetAsync((void*)(ws + BARO), 0, 64, stream);

  HeadPtrs hp{time_b, visit_b, tcont_b, irr0_b, irr1_b, cat0_b, cat1_b};
  persist_k<<<256, 512, 0, stream>>>(z_temporal, b_hh0, b_ih1, b_hh1, ws, hp);

  Keys ky{kk[0][0], kk[0][1], kk[1][0], kk[1][1], kk[2][0], kk[2][1],
          kk[3][0], kk[3][1], kk[4][0], kk[4][1]};
  final_k<<<256, 256, 0, stream>>>(ws, out, ky);
}

// Round 9
// 7987.015 us; speedup vs baseline: 2.4889x; 2.4769x over previous
//
#include <hip/hip_runtime.h>
#include <hip/hip_bf16.h>
#include <cstdint>
#include <cstddef>

typedef __bf16 bf16x8 __attribute__((ext_vector_type(8)));
typedef float f32x4 __attribute__((ext_vector_type(4)));
typedef unsigned short ushort_t;

// ---------------- sizes: B=256, T=256, ZS=128, ZT=64, H=512, 3H=1536

// ---------------- workspace layout (float offsets)
static constexpr size_t ACC0 = 0;                  // [256][1536] f32 static part of xp0
static constexpr size_t SHH  = 393216;             // [256][512] static_h
static constexpr size_t HID  = 524288;             // [256][512] fc1 hidden
static constexpr size_t H0F  = 655360;             // [2][256][512] f32 ping-pong h0 (coherent access only)
static constexpr size_t H1F  = 917504;             // [2][256][512] f32 ping-pong h1 (coherent access only)
static constexpr size_t LOGB = 1179648;            // [256][256][64] f32 head logits
static constexpr size_t WTH  = 5373952;            // [512][64] f32 gathered head weights
static constexpr size_t H0S  = 5406720;            // (unused spare)
static constexpr size_t H1S  = 5799936;            // (unused spare)
static constexpr size_t WB1  = 6193152;            // [32][32][3][3][64][8] bf16 L1 weights
static constexpr size_t WA0  = 8552448;            // [18][32][3][3][64][8] bf16 L0 weights
static constexpr size_t WH   = 9879552;            // [16][4][3][64][8] bf16 head weights
static constexpr size_t BARO = 9928704;            // barrier: 512 slots x 32 u32 + go line
// aliases into LOGB (consumed before step loop writes LOGB)
static constexpr size_t FC1T = LOGB;
static constexpr size_t FC2T = LOGB + 65536;
static constexpr size_t WIS  = FC2T + 262144;

// ---------------- output layout (float offsets)
static constexpr size_t O_SCONT = 0;
static constexpr size_t O_SCAT  = 4096;
static constexpr size_t O_TCONT = 6656;
static constexpr size_t O_IRR0  = 2103808;
static constexpr size_t O_IRR1  = 2234880;
static constexpr size_t O_CAT0  = 2365952;
static constexpr size_t O_CAT1  = 2890240;
static constexpr size_t O_VMASK = 3938816;
static constexpr size_t O_VTIME = 4004352;

// ---------------- threefry2x32-20
__host__ __device__ inline void tf2x32(unsigned k0, unsigned k1, unsigned x0, unsigned x1,
                                       unsigned* o0, unsigned* o1) {
  unsigned ks2 = k0 ^ k1 ^ 0x1BD11BDAu;
#define TFR(r) { x0 += x1; x1 = (x1 << (r)) | (x1 >> (32 - (r))); x1 ^= x0; }
  x0 += k0; x1 += k1;
  TFR(13) TFR(15) TFR(26) TFR(6)
  x0 += k1; x1 += ks2 + 1u;
  TFR(17) TFR(29) TFR(16) TFR(24)
  x0 += ks2; x1 += k0 + 2u;
  TFR(13) TFR(15) TFR(26) TFR(6)
  x0 += k0; x1 += k1 + 3u;
  TFR(17) TFR(29) TFR(16) TFR(24)
  x0 += k1; x1 += ks2 + 4u;
  TFR(13) TFR(15) TFR(26) TFR(6)
  x0 += ks2; x1 += k0 + 5u;
#undef TFR
  *o0 = x0; *o1 = x1;
}

__device__ inline float rng_u01(unsigned k0, unsigned k1, unsigned idx) {
  unsigned o0, o1;
  tf2x32(k0, k1, 0u, idx, &o0, &o1);
  unsigned bits = o0 ^ o1;
  return __uint_as_float((bits >> 9) | 0x3f800000u) - 1.0f;
}

__device__ inline float sigmoidf_(float x) { return 1.0f / (1.0f + expf(-x)); }

// ---------------- coherent (system-scope, cache-bypassing) access helpers
__device__ inline unsigned long long cld64(const float* p) {
  return __hip_atomic_load((const unsigned long long*)p, __ATOMIC_RELAXED, __HIP_MEMORY_SCOPE_SYSTEM);
}
__device__ inline float cldf(const float* p) {
  unsigned u = __hip_atomic_load((const unsigned*)p, __ATOMIC_RELAXED, __HIP_MEMORY_SCOPE_SYSTEM);
  return __uint_as_float(u);
}
__device__ inline void cstf(float* p, float v) {
  __hip_atomic_store((unsigned*)p, __float_as_uint(v), __ATOMIC_RELAXED, __HIP_MEMORY_SCOPE_SYSTEM);
}

// ---------------- tiled transpose
__global__ __launch_bounds__(256) void transpose_k(const float* __restrict__ src, float* __restrict__ dst,
                                                   int J, int K, int srcStride, int dstStride) {
  __shared__ float tile[32][33];
  int kb = blockIdx.x * 32, jb = blockIdx.y * 32;
  int tx = threadIdx.x & 31, ty = threadIdx.x >> 5;
  #pragma unroll
  for (int r = 0; r < 4; ++r) {
    int j = jb + ty + r * 8, k = kb + tx;
    if (j < J && k < K) tile[ty + r * 8][tx] = src[(size_t)j * srcStride + k];
  }
  __syncthreads();
  #pragma unroll
  for (int r = 0; r < 4; ++r) {
    int k = kb + ty + r * 8, j = jb + tx;
    if (k < K && j < J) dst[(size_t)k * dstStride + j] = tile[tx][ty + r * 8];
  }
}

// ---------------- gather head weights into wtH[512][64] (cols 60..63 zero)
__global__ void hgather_k(const float* __restrict__ time_w, const float* __restrict__ visit_w,
                          const float* __restrict__ tcont_w, const float* __restrict__ irr0_w,
                          const float* __restrict__ irr1_w, const float* __restrict__ cat0_w,
                          const float* __restrict__ cat1_w, float* __restrict__ wtH) {
  int c = blockIdx.x;
  if (c >= 60) {
    for (int k = threadIdx.x; k < 512; k += blockDim.x) wtH[(size_t)k * 64 + c] = 0.0f;
    return;
  }
  const float* src;
  if (c == 0) src = time_w;
  else if (c == 1) src = visit_w;
  else if (c < 34) src = tcont_w + (size_t)(c - 2) * 512;
  else if (c == 34) src = irr0_w;
  else if (c == 35) src = irr1_w;
  else if (c < 44) src = cat0_w + (size_t)(c - 36) * 512;
  else src = cat1_w + (size_t)(c - 44) * 512;
  for (int k = threadIdx.x; k < 512; k += blockDim.x) wtH[(size_t)k * 64 + c] = src[k];
}

// ---------------- generic fp32 GEMM (pre-loop static path only)
__global__ __launch_bounds__(128) void gemm_k(const float* __restrict__ in, const float* __restrict__ wT,
                                              const float* __restrict__ bias, float* __restrict__ out,
                                              int M, int K, int J, int relu) {
  __shared__ float ibuf[64][34];
  __shared__ float wbuf[64][36];
  int jt = blockIdx.x % (J >> 5), mt = blockIdx.x / (J >> 5);
  int m0 = mt * 32, j0 = jt * 32;
  int tid = threadIdx.x;
  int mq = tid & 15, jq = tid >> 4;
  float acc[2][4] = {{0.f, 0.f, 0.f, 0.f}, {0.f, 0.f, 0.f, 0.f}};
  for (int kc = 0; kc < K; kc += 64) {
    __syncthreads();
    #pragma unroll
    for (int i = 0; i < 16; ++i) {
      int lin = i * 128 + tid;
      int k = lin & 63, m = lin >> 6;
      ibuf[k][m] = in[(size_t)(m0 + m) * K + kc + k];
    }
    #pragma unroll
    for (int i = 0; i < 16; ++i) {
      int lin = i * 128 + tid;
      int c = lin & 31, k = lin >> 5;
      wbuf[k][c] = wT[(size_t)(kc + k) * J + j0 + c];
    }
    __syncthreads();
    #pragma unroll 8
    for (int k = 0; k < 64; ++k) {
      float i0 = ibuf[k][2 * mq], i1 = ibuf[k][2 * mq + 1];
      const float4 w = *(const float4*)&wbuf[k][4 * jq];
      acc[0][0] += i0 * w.x; acc[0][1] += i0 * w.y; acc[0][2] += i0 * w.z; acc[0][3] += i0 * w.w;
      acc[1][0] += i1 * w.x; acc[1][1] += i1 * w.y; acc[1][2] += i1 * w.z; acc[1][3] += i1 * w.w;
    }
  }
  #pragma unroll
  for (int mi = 0; mi < 2; ++mi)
    #pragma unroll
    for (int ji = 0; ji < 4; ++ji) {
      int j = j0 + 4 * jq + ji;
      float v = acc[mi][ji] + bias[j];
      if (relu) v = fmaxf(v, 0.0f);
      out[(size_t)(m0 + 2 * mq + mi) * J + j] = v;
    }
}

// ---------------- weight arrangement into MFMA-fragment order, 3-way bf16 split
__device__ inline void split3_store(float v, ushort_t* p0, ushort_t* p1, ushort_t* p2) {
  __bf16 t0 = (__bf16)v; float r1 = v - (float)t0;
  __bf16 t1 = (__bf16)r1; float r2 = r1 - (float)t1;
  __bf16 t2 = (__bf16)r2;
  *p0 = __builtin_bit_cast(ushort_t, t0);
  *p1 = __builtin_bit_cast(ushort_t, t1);
  *p2 = __builtin_bit_cast(ushort_t, t2);
}

__global__ __launch_bounds__(256) void arrangeB1_k(const float* __restrict__ w_ih1,
                                                   const float* __restrict__ w_hh1,
                                                   ushort_t* __restrict__ dst) {
  int id = blockIdx.x * 256 + threadIdx.x;          // (kc,ht,g,l): 32*32*3*64
  if (id >= 32 * 32 * 3 * 64) return;
  int l = id & 63; int rest = id >> 6;
  int g = rest % 3; rest /= 3;
  int ht = rest & 31; int kc = rest >> 5;
  int n = g * 512 + ht * 16 + (l & 15);
  int kbase = kc * 32 + (l >> 4) * 8;
  size_t ob = (size_t)((kc * 32 + ht) * 3 + g) * 1536 + (size_t)l * 8;
  #pragma unroll
  for (int j = 0; j < 8; ++j) {
    int k = kbase + j;
    float v = (k < 512) ? w_ih1[(size_t)n * 512 + k] : w_hh1[(size_t)n * 512 + (k - 512)];
    split3_store(v, dst + ob + j, dst + ob + 512 + j, dst + ob + 1024 + j);
  }
}

__global__ __launch_bounds__(256) void arrangeA0_k(const float* __restrict__ w_hh0,
                                                   const float* __restrict__ w_ih0,
                                                   ushort_t* __restrict__ dst) {
  int id = blockIdx.x * 256 + threadIdx.x;          // (kc,ht,g,l): 18*32*3*64
  if (id >= 18 * 32 * 3 * 64) return;
  int l = id & 63; int rest = id >> 6;
  int g = rest % 3; rest /= 3;
  int ht = rest & 31; int kc = rest >> 5;
  int n = g * 512 + ht * 16 + (l & 15);
  int kbase = kc * 32 + (l >> 4) * 8;
  size_t ob = (size_t)((kc * 32 + ht) * 3 + g) * 1536 + (size_t)l * 8;
  #pragma unroll
  for (int j = 0; j < 8; ++j) {
    int k = kbase + j;
    float v = (k < 512) ? w_hh0[(size_t)n * 512 + k] : w_ih0[(size_t)n * 576 + (k - 512)];
    split3_store(v, dst + ob + j, dst + ob + 512 + j, dst + ob + 1024 + j);
  }
}

__global__ __launch_bounds__(256) void arrangeH_k(const float* __restrict__ wtH,
                                                  ushort_t* __restrict__ dst) {
  int id = blockIdx.x * 256 + threadIdx.x;          // (kc,ct,l): 16*4*64
  if (id >= 16 * 4 * 64) return;
  int l = id & 63; int rest = id >> 6;
  int ct = rest & 3; int kc = rest >> 2;
  int c = ct * 16 + (l & 15);
  int kbase = kc * 32 + (l >> 4) * 8;
  size_t ob = (size_t)(kc * 4 + ct) * 1536 + (size_t)l * 8;
  #pragma unroll
  for (int j = 0; j < 8; ++j) {
    float v = wtH[(size_t)(kbase + j) * 64 + c];
    split3_store(v, dst + ob + j, dst + ob + 512 + j, dst + ob + 1024 + j);
  }
}

// ---------------- MFMA helpers: 6-product split accumulation (fp32-accurate)
__device__ inline bf16x8 ldb8(const ushort_t* p) { return *reinterpret_cast<const bf16x8*>(p); }

#define MFMA_(A, W, C) __builtin_amdgcn_mfma_f32_16x16x32_bf16((A), (W), (C), 0, 0, 0)

__device__ inline f32x4 mm6(f32x4 acc, bf16x8 a0, bf16x8 a1, bf16x8 a2, const ushort_t* wb) {
  bf16x8 w0 = ldb8(wb), w1 = ldb8(wb + 512), w2 = ldb8(wb + 1024);
  acc = MFMA_(a0, w0, acc); acc = MFMA_(a0, w1, acc); acc = MFMA_(a1, w0, acc);
  acc = MFMA_(a1, w1, acc); acc = MFMA_(a0, w2, acc); acc = MFMA_(a2, w0, acc);
  return acc;
}

__device__ inline void split3v(const float* v8, bf16x8& a0, bf16x8& a1, bf16x8& a2) {
  #pragma unroll
  for (int j = 0; j < 8; ++j) {
    float v = v8[j];
    __bf16 t0 = (__bf16)v; float r1 = v - (float)t0;
    __bf16 t1 = (__bf16)r1; float r2 = r1 - (float)t1;
    a0[j] = t0; a1[j] = t1; a2[j] = (__bf16)r2;
  }
}

struct HeadPtrs {
  const float *time_b, *visit_b, *tcont_b, *irr0_b, *irr1_b, *cat0_b, *cat1_b;
};

__device__ inline float head_bias(const HeadPtrs& hp, int c) {
  if (c == 0) return hp.time_b[0];
  if (c == 1) return hp.visit_b[0];
  if (c < 34) return hp.tcont_b[c - 2];
  if (c == 34) return hp.irr0_b[0];
  if (c == 35) return hp.irr1_b[0];
  if (c < 44) return hp.cat0_b[c - 36];
  return hp.cat1_b[c - 44];
}

// ---------------- fence-free flat barrier: 512 slots (128B apart) + go line.
// All flags via system-scope relaxed atomics (coherent point, no cache ops).
// Data ordering: coherent data stores drained (vmcnt) before arrival store.
__device__ inline void flatbar(unsigned* arr, unsigned* go, int s, int blk, int tid) {
  const unsigned gen = (unsigned)(s + 1);
  __syncthreads();                     // all waves drain their vmcnt before s_barrier
  asm volatile("s_waitcnt vmcnt(0)" ::: "memory");
  if (tid == 0)
    __hip_atomic_store(&arr[blk * 32], gen, __ATOMIC_RELAXED, __HIP_MEMORY_SCOPE_SYSTEM);
  if (blk == 0) {
    for (int i = tid; i < 512; i += 256) {
      int guard = 0;
      while (__hip_atomic_load(&arr[i * 32], __ATOMIC_RELAXED, __HIP_MEMORY_SCOPE_SYSTEM) < gen) {
        __builtin_amdgcn_s_sleep(4);
        if (++guard > 40000000) break;   // safety valve (never expected)
      }
    }
    __syncthreads();
    if (tid == 0)
      __hip_atomic_store(go, gen, __ATOMIC_RELAXED, __HIP_MEMORY_SCOPE_SYSTEM);
  }
  if (tid == 0) {
    int guard = 0;
    while (__hip_atomic_load(go, __ATOMIC_RELAXED, __HIP_MEMORY_SCOPE_SYSTEM) < gen) {
      __builtin_amdgcn_s_sleep(2);
      if (++guard > 40000000) break;
    }
  }
  asm volatile("" ::: "memory");
  __syncthreads();
}

// ---------------- persistent fused per-step MFMA kernel (512 blocks x 256 thr, 2/CU)
// even blk = job B (h1 update, step s-1), odd blk = job A (h0 update, step s)
//   idx = blk>>1: ht = idx&31, bt = idx>>5 ; waves: mt = wv&1 (16-row M-tile), kh = wv>>1 (K half)
// odd blocks with ht<4 also compute C head logits (ct = ht) for t = s-2
__global__ __launch_bounds__(256, 2) void persist_k(
    const float* __restrict__ z_temporal,
    const float* __restrict__ b_hh0,
    const float* __restrict__ b_ih1, const float* __restrict__ b_hh1,
    float* __restrict__ ws, HeadPtrs hp)
{
  __shared__ f32x4 red[2][5][64];   // [mt][vec][lane] = 10 KB
  const int blk = blockIdx.x, tid = threadIdx.x;
  const int wv = tid >> 6, l = tid & 63, lm = l & 15, lq = l >> 4;
  const int mt = wv & 1, kh = wv >> 1;
  const int job = blk & 1;
  const int idx = blk >> 1;
  const int ht = idx & 31, bt = idx >> 5;
  const int b0 = bt * 32 + mt * 16;
  const int hc = ht * 16;
  const size_t arow = (size_t)(b0 + lm) * 512 + (size_t)lq * 8;
  const bool doC = (job == 1) && (ht < 4);

  float* h0f = ws + H0F;
  float* h1f = ws + H1F;
  unsigned* arr = (unsigned*)(ws + BARO);
  unsigned* go  = arr + 512 * 32;

  for (int s = 0; s <= 257; ++s) {
    f32x4 vr = {}, vz = {}, vn = {}, vni = {}, va = {};
    const bool actB = (job == 0) && s >= 1 && s <= 256;
    const bool actA = (job == 1) && s <= 255;
    const bool actC = doC && s >= 2;

    if (actB) {
      const float* act = (kh == 0) ? (h0f + (size_t)((s - 1) & 1) * 131072)
                                   : (h1f + (size_t)(s & 1) * 131072);
      const ushort_t* wbB = (const ushort_t*)(ws + WB1) + (size_t)ht * 4608 + (size_t)l * 8
                            + (size_t)(kh * 16) * 147456;
      #pragma unroll 2
      for (int kcl = 0; kcl < 16; ++kcl) {
        const float* p = act + arow + (size_t)kcl * 32;
        union { unsigned long long u[4]; float f[8]; } vv;
        vv.u[0] = cld64(p); vv.u[1] = cld64(p + 2); vv.u[2] = cld64(p + 4); vv.u[3] = cld64(p + 6);
        bf16x8 a0, a1, a2; split3v(vv.f, a0, a1, a2);
        const ushort_t* wb = wbB + (size_t)kcl * 147456;
        vr = mm6(vr, a0, a1, a2, wb);
        vz = mm6(vz, a0, a1, a2, wb + 1536);
        vn = mm6(vn, a0, a1, a2, wb + 3072);
      }
      if (kh == 1) { red[mt][0][l] = vr; red[mt][1][l] = vz; red[mt][2][l] = vn; }
    } else if (actA) {
      const float* act = h0f + (size_t)((s + 1) & 1) * 131072;
      const ushort_t* wbA = (const ushort_t*)(ws + WA0) + (size_t)ht * 4608 + (size_t)l * 8;
      const int nkc = kh ? 10 : 8;
      #pragma unroll 2
      for (int kcl = 0; kcl < nkc; ++kcl) {
        const int kcg = kh * 8 + kcl;
        bf16x8 a0, a1, a2;
        if (kcg < 16) {
          const float* p = act + arow + (size_t)kcg * 32;
          union { unsigned long long u[4]; float f[8]; } vv;
          vv.u[0] = cld64(p); vv.u[1] = cld64(p + 2); vv.u[2] = cld64(p + 4); vv.u[3] = cld64(p + 6);
          split3v(vv.f, a0, a1, a2);
        } else {
          const float* zp = z_temporal + ((size_t)(b0 + lm) * 256 + s) * 64 + (kcg - 16) * 32 + lq * 8;
          float4 q0 = *(const float4*)zp;
          float4 q1 = *(const float4*)(zp + 4);
          float vals[8] = {q0.x, q0.y, q0.z, q0.w, q1.x, q1.y, q1.z, q1.w};
          split3v(vals, a0, a1, a2);
        }
        const ushort_t* wb = wbA + (size_t)kcg * 147456;
        vr = mm6(vr, a0, a1, a2, wb);
        vz = mm6(vz, a0, a1, a2, wb + 1536);
        if (kcg < 16) vn  = mm6(vn,  a0, a1, a2, wb + 3072);
        else          vni = mm6(vni, a0, a1, a2, wb + 3072);
      }
      if (kh == 1) {
        red[mt][0][l] = vr; red[mt][1][l] = vz; red[mt][2][l] = vn; red[mt][3][l] = vni;
      }
    }

    if (actC) {
      const float* actH = h1f + (size_t)(s & 1) * 131072;
      const ushort_t* wH = (const ushort_t*)(ws + WH) + (size_t)l * 8;
      #pragma unroll 2
      for (int kcl = 0; kcl < 8; ++kcl) {
        const int kc = kh * 8 + kcl;
        const float* p = actH + arow + (size_t)kc * 32;
        union { unsigned long long u[4]; float f[8]; } vv;
        vv.u[0] = cld64(p); vv.u[1] = cld64(p + 2); vv.u[2] = cld64(p + 4); vv.u[3] = cld64(p + 6);
        bf16x8 a0, a1, a2; split3v(vv.f, a0, a1, a2);
        va = mm6(va, a0, a1, a2, wH + (size_t)(kc * 4 + ht) * 1536);
      }
      if (kh == 1) red[mt][4][l] = va;
    }

    __syncthreads();

    // ---------- finalize (kh==0 waves) ----------
    if (actB && kh == 0) {
      const f32x4 r4 = vr + red[mt][0][l];
      const f32x4 z4 = vz + red[mt][1][l];
      const f32x4 nh4 = red[mt][2][l];
      const float* h1f_old = h1f + (size_t)(s & 1) * 131072;
      float* h1f_cur = h1f + (size_t)((s - 1) & 1) * 131072;
      const int h = hc + lm;
      #pragma unroll
      for (int r = 0; r < 4; ++r) {
        const int b = b0 + lq * 4 + r;
        const float rr = r4[r] + b_ih1[h] + b_hh1[h];
        const float zz = z4[r] + b_ih1[512 + h] + b_hh1[512 + h];
        const float ni = vn[r] + b_ih1[1024 + h];
        const float nh = nh4[r] + b_hh1[1024 + h];
        const float rg = sigmoidf_(rr), zg = sigmoidf_(zz);
        const float n = tanhf(ni + rg * nh);
        const float hold = cldf(&h1f_old[(size_t)b * 512 + h]);
        cstf(&h1f_cur[(size_t)b * 512 + h], (1.0f - zg) * n + zg * hold);
      }
    } else if (actA && kh == 0) {
      const f32x4 r4 = vr + red[mt][0][l];
      const f32x4 z4 = vz + red[mt][1][l];
      const f32x4 nh4 = vn + red[mt][2][l];
      const f32x4 ni4 = red[mt][3][l];
      const float* h0f_old = h0f + (size_t)((s + 1) & 1) * 131072;
      float* h0f_cur = h0f + (size_t)(s & 1) * 131072;
      const float* acc0 = ws + ACC0;
      const int h = hc + lm;
      #pragma unroll
      for (int r = 0; r < 4; ++r) {
        const int b = b0 + lq * 4 + r;
        const float* ac = acc0 + (size_t)b * 1536;
        const float rr = r4[r] + ac[h] + b_hh0[h];
        const float zz = z4[r] + ac[512 + h] + b_hh0[512 + h];
        const float ni = ni4[r] + ac[1024 + h];
        const float nh = nh4[r] + b_hh0[1024 + h];
        const float rg = sigmoidf_(rr), zg = sigmoidf_(zz);
        const float n = tanhf(ni + rg * nh);
        const float hold = cldf(&h0f_old[(size_t)b * 512 + h]);
        cstf(&h0f_cur[(size_t)b * 512 + h], (1.0f - zg) * n + zg * hold);
      }
    }

    if (actC && kh == 0) {
      const f32x4 v4 = va + red[mt][4][l];
      const int t = s - 2;
      const int c = ht * 16 + lm;
      if (c < 60) {
        const float bias = head_bias(hp, c);
        float* lg = ws + LOGB;
        #pragma unroll
        for (int r = 0; r < 4; ++r) {
          const int b = b0 + lq * 4 + r;
          lg[((size_t)b * 256 + t) * 64 + c] = v4[r] + bias;  // normal store: consumed post-kernel
        }
      }
    }

    flatbar(arr, go, s, blk, tid);
  }
}

// ---------------- static heads
__global__ __launch_bounds__(64) void static_heads_k(const float* __restrict__ sh_buf,
    const float* __restrict__ scont_w, const float* __restrict__ scont_b,
    const float* __restrict__ scat_w, const float* __restrict__ scat_b,
    float* __restrict__ out, unsigned ks0, unsigned ks1)
{
  __shared__ float hrow[512];
  __shared__ float xl[10];
  __shared__ float yv[10];
  __shared__ int argsh;
  int b = blockIdx.x, tid = threadIdx.x;
  const float* hr = sh_buf + (size_t)b * 512;
  for (int i = tid; i < 512; i += 64) hrow[i] = hr[i];
  __syncthreads();
  if (tid < 16) {
    float a = 0.f;
    const float* w = scont_w + (size_t)tid * 512;
    for (int k = 0; k < 512; ++k) a += hrow[k] * w[k];
    out[O_SCONT + (size_t)b * 16 + tid] = a + scont_b[tid];
  }
  if (tid < 10) {
    float a = 0.f;
    const float* w = scat_w + (size_t)tid * 512;
    for (int k = 0; k < 512; ++k) a += hrow[k] * w[k];
    a += scat_b[tid];
    float u = rng_u01(ks0, ks1, (unsigned)(b * 10 + tid));
    u = fmaxf(1e-9f, u + 1e-9f);
    float g = -logf(-logf(u));
    xl[tid] = a + g;
  }
  __syncthreads();
  if (tid == 0) {
    float m = xl[0];
    for (int c = 1; c < 10; ++c) m = fmaxf(m, xl[c]);
    float ssum = 0.f;
    for (int c = 0; c < 10; ++c) { yv[c] = expf(xl[c] - m); ssum += yv[c]; }
    int arg = 0; float best = -1.0f;
    for (int c = 0; c < 10; ++c) { yv[c] = yv[c] / ssum; if (yv[c] > best) { best = yv[c]; arg = c; } }
    argsh = arg;
  }
  __syncthreads();
  if (tid < 10) {
    float y = yv[tid];
    out[O_SCAT + (size_t)b * 10 + tid] = (tid == argsh) ? ((1.0f + y) - y) : 0.0f;
  }
}

// ---------------- final scans + sampling + emission
struct Keys { unsigned kv0, kv1, ki00, ki01, ki10, ki11, kc00, kc01, kc10, kc11; };

__global__ __launch_bounds__(256) void final_k(const float* __restrict__ ws, float* __restrict__ out, Keys ky)
{
  __shared__ float sh[256];
  __shared__ unsigned shu[256];
  int b = blockIdx.x, t = threadIdx.x;
  int idx = b * 256 + t;
  const float* lg = ws + LOGB + (size_t)idx * 64;
  float l0 = lg[0], l1 = lg[1], l34 = lg[34], l35 = lg[35];

  float dt = fmaxf(l0, 0.0f) + log1pf(expf(-fabsf(l0)));
  sh[t] = dt; __syncthreads();
  for (int off = 1; off < 256; off <<= 1) {
    float v = (t >= off) ? sh[t - off] : 0.0f;
    __syncthreads();
    sh[t] += v;
    __syncthreads();
  }
  float vt = sh[t];
  float denom = sh[255] + 1e-8f;
  out[O_VTIME + idx] = vt / denom;
  __syncthreads();

  float pv = sigmoidf_(l1);
  float uv = rng_u01(ky.kv0, ky.kv1, (unsigned)idx);
  shu[t] = (t == 0) ? 1u : (uv < pv ? 1u : 0u);
  __syncthreads();
  for (int off = 1; off < 256; off <<= 1) {
    unsigned v = (t >= off) ? shu[t - off] : 1u;
    __syncthreads();
    shu[t] &= v;
    __syncthreads();
  }
  float mask = (float)shu[t];
  out[O_VMASK + idx] = mask;
  __syncthreads();

  {
    float hz = sigmoidf_(l34);
    float u = rng_u01(ky.ki00, ky.ki01, (unsigned)idx);
    shu[t] = (u < hz) ? 1u : 0u;
    __syncthreads();
    for (int off = 1; off < 256; off <<= 1) {
      unsigned v = (t >= off) ? shu[t - off] : 0u;
      __syncthreads();
      shu[t] |= v;
      __syncthreads();
    }
    float st = (float)shu[t];
    out[O_IRR0 + (size_t)idx * 2]     = (1.0f - st) * mask;
    out[O_IRR0 + (size_t)idx * 2 + 1] = st * mask;
    __syncthreads();
  }
  {
    float hz = sigmoidf_(l35);
    float u = rng_u01(ky.ki10, ky.ki11, (unsigned)idx);
    shu[t] = (u < hz) ? 1u : 0u;
    __syncthreads();
    for (int off = 1; off < 256; off <<= 1) {
      unsigned v = (t >= off) ? shu[t - off] : 0u;
      __syncthreads();
      shu[t] |= v;
      __syncthreads();
    }
    float st = (float)shu[t];
    out[O_IRR1 + (size_t)idx * 2]     = (1.0f - st) * mask;
    out[O_IRR1 + (size_t)idx * 2 + 1] = st * mask;
  }

  #pragma unroll
  for (int c = 0; c < 32; ++c)
    out[O_TCONT + (size_t)idx * 32 + c] = lg[2 + c] * mask;

  {
    float x[8], y[8];
    float m = -1e30f;
    #pragma unroll
    for (int c = 0; c < 8; ++c) {
      float u = rng_u01(ky.kc00, ky.kc01, (unsigned)idx * 8u + c);
      u = fmaxf(1e-9f, u + 1e-9f);
      float g = -logf(-logf(u));
      x[c] = lg[36 + c] + g;
      m = fmaxf(m, x[c]);
    }
    float ssum = 0.f;
    #pragma unroll
    for (int c = 0; c < 8; ++c) { y[c] = expf(x[c] - m); ssum += y[c]; }
    int arg = 0; float best = -1.0f;
    #pragma unroll
    for (int c = 0; c < 8; ++c) { y[c] /= ssum; if (y[c] > best) { best = y[c]; arg = c; } }
    #pragma unroll
    for (int c = 0; c < 8; ++c)
      out[O_CAT0 + (size_t)idx * 8 + c] = (c == arg) ? ((1.0f + y[c]) - y[c]) * mask : 0.0f;
  }
  {
    float x[16], y[16];
    float m = -1e30f;
    #pragma unroll
    for (int c = 0; c < 16; ++c) {
      float u = rng_u01(ky.kc10, ky.kc11, (unsigned)idx * 16u + c);
      u = fmaxf(1e-9f, u + 1e-9f);
      float g = -logf(-logf(u));
      x[c] = lg[44 + c] + g;
      m = fmaxf(m, x[c]);
    }
    float ssum = 0.f;
    #pragma unroll
    for (int c = 0; c < 16; ++c) { y[c] = expf(x[c] - m); ssum += y[c]; }
    int arg = 0; float best = -1.0f;
    #pragma unroll
    for (int c = 0; c < 16; ++c) { y[c] /= ssum; if (y[c] > best) { best = y[c]; arg = c; } }
    #pragma unroll
    for (int c = 0; c < 16; ++c)
      out[O_CAT1 + (size_t)idx * 16 + c] = (c == arg) ? ((1.0f + y[c]) - y[c]) * mask : 0.0f;
  }
}

// ---------------- host entry
extern "C" void kernel_launch(void* const* d_in, const int* in_sizes, int n_in,
                              void* d_out, int out_size, void* d_ws, size_t ws_size,
                              hipStream_t stream)
{
  (void)in_sizes; (void)n_in; (void)out_size; (void)ws_size;
  const float* z_static   = (const float*)d_in[0];
  const float* z_temporal = (const float*)d_in[1];
  const float* fc1_w = (const float*)d_in[2];
  const float* fc1_b = (const float*)d_in[3];
  const float* fc2_w = (const float*)d_in[4];
  const float* fc2_b = (const float*)d_in[5];
  const float* w_ih0 = (const float*)d_in[6];
  const float* w_hh0 = (const float*)d_in[7];
  const float* b_ih0 = (const float*)d_in[8];
  const float* b_hh0 = (const float*)d_in[9];
  const float* w_ih1 = (const float*)d_in[10];
  const float* w_hh1 = (const float*)d_in[11];
  const float* b_ih1 = (const float*)d_in[12];
  const float* b_hh1 = (const float*)d_in[13];
  const float* time_w = (const float*)d_in[14];
  const float* time_b = (const float*)d_in[15];
  const float* visit_w = (const float*)d_in[16];
  const float* visit_b = (const float*)d_in[17];
  const float* tcont_w = (const float*)d_in[18];
  const float* tcont_b = (const float*)d_in[19];
  const float* irr0_w = (const float*)d_in[20];
  const float* irr0_b = (const float*)d_in[21];
  const float* irr1_w = (const float*)d_in[22];
  const float* irr1_b = (const float*)d_in[23];
  const float* cat0_w = (const float*)d_in[24];
  const float* cat0_b = (const float*)d_in[25];
  const float* cat1_w = (const float*)d_in[26];
  const float* cat1_b = (const float*)d_in[27];
  const float* scont_w = (const float*)d_in[28];
  const float* scont_b = (const float*)d_in[29];
  const float* scat_w = (const float*)d_in[30];
  const float* scat_b = (const float*)d_in[31];
  float* ws = (float*)d_ws;
  float* out = (float*)d_out;

  // static-path transposes (aliased into LOGB region, consumed pre-loop)
  transpose_k<<<dim3(4, 16), 256, 0, stream>>>(fc1_w, ws + FC1T, 512, 128, 128, 512);
  transpose_k<<<dim3(16, 16), 256, 0, stream>>>(fc2_w, ws + FC2T, 512, 512, 512, 512);
  transpose_k<<<dim3(16, 48), 256, 0, stream>>>(w_ih0 + 64, ws + WIS, 1536, 512, 576, 1536);
  hgather_k<<<64, 128, 0, stream>>>(time_w, visit_w, tcont_w, irr0_w, irr1_w, cat0_w, cat1_w, ws + WTH);

  // static path: static_h, acc0
  gemm_k<<<8 * 16, 128, 0, stream>>>(z_static, ws + FC1T, fc1_b, ws + HID, 256, 128, 512, 1);
  gemm_k<<<8 * 16, 128, 0, stream>>>(ws + HID, ws + FC2T, fc2_b, ws + SHH, 256, 512, 512, 0);
  gemm_k<<<8 * 48, 128, 0, stream>>>(ws + SHH, ws + WIS, b_ih0, ws + ACC0, 256, 512, 1536, 0);

  // arrange MFMA weight fragments (3-way bf16 split)
  arrangeB1_k<<<(32 * 32 * 3 * 64 + 255) / 256, 256, 0, stream>>>(w_ih1, w_hh1, (ushort_t*)(ws + WB1));
  arrangeA0_k<<<(18 * 32 * 3 * 64 + 255) / 256, 256, 0, stream>>>(w_hh0, w_ih0, (ushort_t*)(ws + WA0));
  arrangeH_k<<<(16 * 4 * 64 + 255) / 256, 256, 0, stream>>>(ws + WTH, (ushort_t*)(ws + WH));

  // RNG keys: key(42) = (0,42); 6 children (partitionable fold-in)
  unsigned kk[6][2];
  for (int i = 0; i < 6; ++i) tf2x32(0u, 42u, 0u, (unsigned)i, &kk[i][0], &kk[i][1]);

  static_heads_k<<<256, 64, 0, stream>>>(ws + SHH, scont_w, scont_b, scat_w, scat_b, out,
                                         kk[5][0], kk[5][1]);

  // zero initial hidden states (parity 1) + barrier region (512*32 slots + go line)
  hipMemsetAsync((void*)(ws + H0F + 131072), 0, 131072 * sizeof(float), stream);
  hipMemsetAsync((void*)(ws + H1F + 131072), 0, 131072 * sizeof(float), stream);
  hipMemsetAsync((void*)(ws + BARO), 0, (512 * 32 + 64) * sizeof(unsigned), stream);

  HeadPtrs hp{time_b, visit_b, tcont_b, irr0_b, irr1_b, cat0_b, cat1_b};
  persist_k<<<512, 256, 0, stream>>>(z_temporal, b_hh0, b_ih1, b_hh1, ws, hp);

  Keys ky{kk[0][0], kk[0][1], kk[1][0], kk[1][1], kk[2][0], kk[2][1],
          kk[3][0], kk[3][1], kk[4][0], kk[4][1]};
  final_k<<<256, 256, 0, stream>>>(ws, out, ky);
}